// Round 1
// baseline (258.734 us; speedup 1.0000x reference)
//
#include <hip/hip_runtime.h>
#include <stdint.h>

typedef unsigned short u16;
using f32x4 = __attribute__((ext_vector_type(4))) float;
using s16x8 = __attribute__((ext_vector_type(8))) short;

#define MFMA_BF16(a, b, c) __builtin_amdgcn_mfma_f32_16x16x32_bf16((a), (b), (c), 0, 0, 0)

#define GLOAD_LDS16(gptr, lptr)                                                               \
  __builtin_amdgcn_global_load_lds((const __attribute__((address_space(1))) uint32_t*)(gptr), \
                                   (__attribute__((address_space(3))) uint32_t*)(lptr), 16, 0, 0)

__device__ __forceinline__ u16 f2bf(float f) {
  union { float f; uint32_t u; } v; v.f = f;
  uint32_t r = v.u + 0x7fffu + ((v.u >> 16) & 1u);
  return (u16)(r >> 16);
}
__device__ __forceinline__ float bf2f(u16 h) {
  union { uint32_t u; float f; } v; v.u = ((uint32_t)h) << 16;
  return v.f;
}

// ---------------- K1: convert weights fp32 -> bf16 ----------------
__global__ void k_convert_w(const float* __restrict__ wq, const float* __restrict__ wo,
                            u16* __restrict__ wqb, u16* __restrict__ wob) {
  int i = blockIdx.x * 256 + threadIdx.x;
  const int nq = 1536 * 512 / 4;  // 196608 float4s
  const int no = 512 * 512 / 4;   //  65536 float4s
  if (i < nq) {
    float4 v = ((const float4*)wq)[i];
    u16* o = wqb + i * 4;
    o[0] = f2bf(v.x); o[1] = f2bf(v.y); o[2] = f2bf(v.z); o[3] = f2bf(v.w);
  } else if (i < nq + no) {
    int j = i - nq;
    float4 v = ((const float4*)wo)[j];
    u16* o = wob + j * 4;
    o[0] = f2bf(v.x); o[1] = f2bf(v.y); o[2] = f2bf(v.z); o[3] = f2bf(v.w);
  }
}

// ---------------- K2: x [b][c][t] f32 -> xT [b][t][c] bf16 ----------------
__global__ void k_transpose_x(const float* __restrict__ x, u16* __restrict__ xT) {
  __shared__ u16 tile[64][65];
  int b = blockIdx.z, c0 = blockIdx.y * 64, t0 = blockIdx.x * 64;
  const float* xp = x + ((size_t)b * 512 + c0) * 4096 + t0;
#pragma unroll
  for (int i = 0; i < 16; ++i) {
    int idx = threadIdx.x + i * 256;
    int r = idx >> 6, col = idx & 63;         // r = c, col = t
    tile[r][col] = f2bf(xp[(size_t)r * 4096 + col]);
  }
  __syncthreads();
  u16* op = xT + ((size_t)b * 4096 + t0) * 512 + c0;
#pragma unroll
  for (int i = 0; i < 16; ++i) {
    int idx = threadIdx.x + i * 256;
    int r = idx >> 6, col = idx & 63;         // r = t, col = c
    op[(size_t)r * 512 + col] = tile[col][r];
  }
}

// ---------------- K3: qkv GEMM  C[b][m][n] = sum_k A[m][k]*BT[n][k] ----------------
// A = w_qkv bf16 [1536][512]; BT = xT [b][4096][512]; C = qkv bf16 [b][1536][4096]
__launch_bounds__(256, 2)
__global__ void k_gemm_qkv(const u16* __restrict__ A, const u16* __restrict__ BT,
                           u16* __restrict__ C) {
  __shared__ s16x8 As8[1024];  // [128 rows][8 chunks], swizzled chunk = logical ^ (row&7)
  __shared__ s16x8 Bs8[1024];
  int b = blockIdx.z;
  int m0 = blockIdx.y * 128, n0 = blockIdx.x * 128;
  const u16* Ab = A + (size_t)m0 * 512;
  const u16* Bb = BT + ((size_t)b * 4096 + n0) * 512;
  int tid = threadIdx.x, w = tid >> 6, lane = tid & 63;
  int wm = (w >> 1) * 64, wn = (w & 1) * 64;
  f32x4 acc[4][4] = {};
  for (int kt = 0; kt < 8; ++kt) {
    if (kt) __syncthreads();
#pragma unroll
    for (int it = 0; it < 4; ++it) {
      int L = (w * 4 + it) * 64 + lane;
      int r = L >> 3;
      int lc = (L & 7) ^ (r & 7);
      GLOAD_LDS16(Ab + (size_t)r * 512 + kt * 64 + lc * 8, ((char*)As8) + (w * 4 + it) * 1024);
      GLOAD_LDS16(Bb + (size_t)r * 512 + kt * 64 + lc * 8, ((char*)Bs8) + (w * 4 + it) * 1024);
    }
    asm volatile("s_waitcnt vmcnt(0)");
    __syncthreads();
#pragma unroll
    for (int kk = 0; kk < 2; ++kk) {
      int cb = kk * 4 + (lane >> 4);
      s16x8 af[4], bfr[4];
#pragma unroll
      for (int mi = 0; mi < 4; ++mi) {
        int r = wm + mi * 16 + (lane & 15);
        af[mi] = As8[r * 8 + (cb ^ (r & 7))];
      }
#pragma unroll
      for (int ni = 0; ni < 4; ++ni) {
        int r = wn + ni * 16 + (lane & 15);
        bfr[ni] = Bs8[r * 8 + (cb ^ (r & 7))];
      }
#pragma unroll
      for (int mi = 0; mi < 4; ++mi)
#pragma unroll
        for (int ni = 0; ni < 4; ++ni)
          acc[mi][ni] = MFMA_BF16(af[mi], bfr[ni], acc[mi][ni]);
    }
  }
  u16* Cb = C + ((size_t)b * 1536 + m0) * 4096 + n0;
#pragma unroll
  for (int mi = 0; mi < 4; ++mi)
#pragma unroll
    for (int ni = 0; ni < 4; ++ni)
#pragma unroll
      for (int j = 0; j < 4; ++j) {
        int mm = wm + mi * 16 + (lane >> 4) * 4 + j;
        int nn = wn + ni * 16 + (lane & 15);
        Cb[(size_t)mm * 4096 + nn] = f2bf(acc[mi][ni][j]);
      }
}

// ---------------- K4: q softmax over d (64) -> qT [bh][t][d] bf16, * SCALE ----------------
__global__ void k_softmax_q(const u16* __restrict__ qkv, u16* __restrict__ qT) {
  int idx = blockIdx.x * 256 + threadIdx.x;  // (b,h,t), 262144 total
  int t = idx & 4095;
  int bh = idx >> 12;
  int b = bh >> 3, h = bh & 7;
  const u16* qp = qkv + ((size_t)b * 1536 + h * 64) * 4096 + t;
  float v[64];
  float mx = -1e30f;
#pragma unroll
  for (int d = 0; d < 64; ++d) { v[d] = bf2f(qp[(size_t)d * 4096]); mx = fmaxf(mx, v[d]); }
  float s = 0.f;
#pragma unroll
  for (int d = 0; d < 64; ++d) { v[d] = __expf(v[d] - mx); s += v[d]; }
  float sc = 0.125f / s;  // SCALE = 64^-0.5
  u16* op = qT + ((size_t)bh * 4096 + t) * 64;
#pragma unroll
  for (int d8 = 0; d8 < 8; ++d8) {
    s16x8 o;
#pragma unroll
    for (int j = 0; j < 8; ++j) o[j] = (short)f2bf(v[d8 * 8 + j] * sc);
    ((s16x8*)op)[d8] = o;
  }
}

// ---------------- K5: k softmax over t (4096), in place on qkv's k region ----------------
__global__ void k_softmax_k(u16* __restrict__ kp) {
  int row = blockIdx.x;           // (b, h*64+d): 4096 rows
  int b = row >> 9, rem = row & 511;
  u16* p = kp + ((size_t)b * 1536 + 512 + rem) * 4096;
  int tid = threadIdx.x, lane = tid & 63, w = tid >> 6;
  s16x8 c0 = ((const s16x8*)p)[tid];
  s16x8 c1 = ((const s16x8*)p)[tid + 256];
  float v[16];
#pragma unroll
  for (int j = 0; j < 8; ++j) { v[j] = bf2f((u16)c0[j]); v[8 + j] = bf2f((u16)c1[j]); }
  float mx = -1e30f;
#pragma unroll
  for (int j = 0; j < 16; ++j) mx = fmaxf(mx, v[j]);
#pragma unroll
  for (int off = 32; off; off >>= 1) mx = fmaxf(mx, __shfl_xor(mx, off));
  __shared__ float redm[4], reds[4];
  if (lane == 0) redm[w] = mx;
  __syncthreads();
  mx = fmaxf(fmaxf(redm[0], redm[1]), fmaxf(redm[2], redm[3]));
  float s = 0.f;
#pragma unroll
  for (int j = 0; j < 16; ++j) { v[j] = __expf(v[j] - mx); s += v[j]; }
#pragma unroll
  for (int off = 32; off; off >>= 1) s += __shfl_xor(s, off);
  if (lane == 0) reds[w] = s;
  __syncthreads();
  s = reds[0] + reds[1] + reds[2] + reds[3];
  float inv = 1.f / s;
  s16x8 o0, o1;
#pragma unroll
  for (int j = 0; j < 8; ++j) { o0[j] = (short)f2bf(v[j] * inv); o1[j] = (short)f2bf(v[8 + j] * inv); }
  ((s16x8*)p)[tid] = o0;
  ((s16x8*)p)[tid + 256] = o1;
}

// ---------------- K6: context  ctxT[bh][e][d] = sum_n v[e][n]*k[d][n]  (bf16 out) ----------
__global__ void k_context(const u16* __restrict__ qkv, u16* __restrict__ ctxT) {
  int bh = blockIdx.x;  // 64
  int b = bh >> 3, h = bh & 7;
  const u16* vbase = qkv + ((size_t)b * 1536 + 1024 + h * 64) * 4096;
  const u16* kbase = qkv + ((size_t)b * 1536 + 512 + h * 64) * 4096;
  int w = threadIdx.x >> 6, lane = threadIdx.x & 63;
  int e0 = w * 16;
  f32x4 acc[4] = {};
  int er = e0 + (lane & 15);
  int nl = (lane >> 4) * 8;
#pragma unroll 2
  for (int n0 = 0; n0 < 4096; n0 += 32) {
    s16x8 a = *(const s16x8*)(vbase + (size_t)er * 4096 + n0 + nl);
#pragma unroll
    for (int ni = 0; ni < 4; ++ni) {
      s16x8 bb = *(const s16x8*)(kbase + (size_t)(ni * 16 + (lane & 15)) * 4096 + n0 + nl);
      acc[ni] = MFMA_BF16(a, bb, acc[ni]);
    }
  }
  u16* cp = ctxT + (size_t)bh * 64 * 64;
#pragma unroll
  for (int ni = 0; ni < 4; ++ni)
#pragma unroll
    for (int j = 0; j < 4; ++j) {
      int e = e0 + (lane >> 4) * 4 + j;
      int d = ni * 16 + (lane & 15);
      cp[e * 64 + d] = f2bf(acc[ni][j]);
    }
}

// ---------------- K7: attn apply  outT[b][t][h*64+e] = sum_d qT[t][d]*ctxT[e][d] ----------
__launch_bounds__(256, 2)
__global__ void k_attn_out(const u16* __restrict__ qT, const u16* __restrict__ ctxT,
                           u16* __restrict__ outT) {
  __shared__ s16x8 Qs[1024];  // [128 t][8 chunks] swizzled
  __shared__ s16x8 Cs[512];   // [64 e][8 chunks] swizzled
  int bh = blockIdx.y;
  int t0 = blockIdx.x * 128;
  int b = bh >> 3, h = bh & 7;
  const u16* qb = qT + ((size_t)bh * 4096 + t0) * 64;
  const u16* cb = ctxT + (size_t)bh * 64 * 64;
  int tid = threadIdx.x, w = tid >> 6, lane = tid & 63;
#pragma unroll
  for (int it = 0; it < 4; ++it) {
    int L = (w * 4 + it) * 64 + lane;
    int r = L >> 3, lc = (L & 7) ^ (r & 7);
    GLOAD_LDS16(qb + (size_t)r * 64 + lc * 8, ((char*)Qs) + (w * 4 + it) * 1024);
  }
#pragma unroll
  for (int it = 0; it < 2; ++it) {
    int L = (w * 2 + it) * 64 + lane;
    int r = L >> 3, lc = (L & 7) ^ (r & 7);
    GLOAD_LDS16(cb + (size_t)r * 64 + lc * 8, ((char*)Cs) + (w * 2 + it) * 1024);
  }
  asm volatile("s_waitcnt vmcnt(0)");
  __syncthreads();
  f32x4 acc[2][4] = {};
#pragma unroll
  for (int kk = 0; kk < 2; ++kk) {
    int cbi = kk * 4 + (lane >> 4);
    s16x8 af[2], bfr[4];
#pragma unroll
    for (int mi = 0; mi < 2; ++mi) {
      int r = w * 32 + mi * 16 + (lane & 15);
      af[mi] = Qs[r * 8 + (cbi ^ (r & 7))];
    }
#pragma unroll
    for (int ni = 0; ni < 4; ++ni) {
      int r = ni * 16 + (lane & 15);
      bfr[ni] = Cs[r * 8 + (cbi ^ (r & 7))];
    }
#pragma unroll
    for (int mi = 0; mi < 2; ++mi)
#pragma unroll
      for (int ni = 0; ni < 4; ++ni)
        acc[mi][ni] = MFMA_BF16(af[mi], bfr[ni], acc[mi][ni]);
  }
  u16* op = outT + ((size_t)b * 4096 + t0) * 512 + h * 64;
#pragma unroll
  for (int mi = 0; mi < 2; ++mi)
#pragma unroll
    for (int ni = 0; ni < 4; ++ni)
#pragma unroll
      for (int j = 0; j < 4; ++j) {
        int t = w * 32 + mi * 16 + (lane >> 4) * 4 + j;
        int e = ni * 16 + (lane & 15);
        op[(size_t)t * 512 + e] = f2bf(acc[mi][ni][j]);
      }
}

// ---------------- K8: w_out GEMM + bias -> y fp32 (d_out) ----------------
// A = w_out bf16 [512][512]; BT = outT [b][4096][512]; y[b][m][n] += b_out[m]
__launch_bounds__(256, 2)
__global__ void k_gemm_wout(const u16* __restrict__ A, const u16* __restrict__ BT,
                            float* __restrict__ Y, const float* __restrict__ bias) {
  __shared__ s16x8 As8[1024];
  __shared__ s16x8 Bs8[1024];
  int b = blockIdx.z;
  int m0 = blockIdx.y * 128, n0 = blockIdx.x * 128;
  const u16* Ab = A + (size_t)m0 * 512;
  const u16* Bb = BT + ((size_t)b * 4096 + n0) * 512;
  int tid = threadIdx.x, w = tid >> 6, lane = tid & 63;
  int wm = (w >> 1) * 64, wn = (w & 1) * 64;
  f32x4 acc[4][4] = {};
  for (int kt = 0; kt < 8; ++kt) {
    if (kt) __syncthreads();
#pragma unroll
    for (int it = 0; it < 4; ++it) {
      int L = (w * 4 + it) * 64 + lane;
      int r = L >> 3;
      int lc = (L & 7) ^ (r & 7);
      GLOAD_LDS16(Ab + (size_t)r * 512 + kt * 64 + lc * 8, ((char*)As8) + (w * 4 + it) * 1024);
      GLOAD_LDS16(Bb + (size_t)r * 512 + kt * 64 + lc * 8, ((char*)Bs8) + (w * 4 + it) * 1024);
    }
    asm volatile("s_waitcnt vmcnt(0)");
    __syncthreads();
#pragma unroll
    for (int kk = 0; kk < 2; ++kk) {
      int cb = kk * 4 + (lane >> 4);
      s16x8 af[4], bfr[4];
#pragma unroll
      for (int mi = 0; mi < 4; ++mi) {
        int r = wm + mi * 16 + (lane & 15);
        af[mi] = As8[r * 8 + (cb ^ (r & 7))];
      }
#pragma unroll
      for (int ni = 0; ni < 4; ++ni) {
        int r = wn + ni * 16 + (lane & 15);
        bfr[ni] = Bs8[r * 8 + (cb ^ (r & 7))];
      }
#pragma unroll
      for (int mi = 0; mi < 4; ++mi)
#pragma unroll
        for (int ni = 0; ni < 4; ++ni)
          acc[mi][ni] = MFMA_BF16(af[mi], bfr[ni], acc[mi][ni]);
    }
  }
  float* Yb = Y + ((size_t)b * 512 + m0) * 4096 + n0;
#pragma unroll
  for (int mi = 0; mi < 4; ++mi)
#pragma unroll
    for (int j = 0; j < 4; ++j) {
      int mm = wm + mi * 16 + (lane >> 4) * 4 + j;
      float bo = bias[m0 + mm];
#pragma unroll
      for (int ni = 0; ni < 4; ++ni) {
        int nn = wn + ni * 16 + (lane & 15);
        Yb[(size_t)mm * 4096 + nn] = acc[mi][ni][j] + bo;
      }
    }
}

// ---------------- K9: GroupNorm partial sums per batch ----------------
__global__ void k_gn_partial(const float* __restrict__ y, float2* __restrict__ part) {
  int b = blockIdx.y, blk = blockIdx.x;  // 64 blocks per batch, 32768 elems each
  const float4* p = (const float4*)(y + ((size_t)b << 21) + (size_t)blk * 32768);
  int tid = threadIdx.x, lane = tid & 63, w = tid >> 6;
  float s = 0.f, ss = 0.f;
#pragma unroll
  for (int i = 0; i < 32; ++i) {
    float4 v = p[tid + i * 256];
    s += v.x + v.y + v.z + v.w;
    ss += v.x * v.x + v.y * v.y + v.z * v.z + v.w * v.w;
  }
#pragma unroll
  for (int off = 32; off; off >>= 1) { s += __shfl_xor(s, off); ss += __shfl_xor(ss, off); }
  __shared__ float sr[4], ssr[4];
  if (lane == 0) { sr[w] = s; ssr[w] = ss; }
  __syncthreads();
  if (tid == 0) {
    float2 o;
    o.x = sr[0] + sr[1] + sr[2] + sr[3];
    o.y = ssr[0] + ssr[1] + ssr[2] + ssr[3];
    part[b * 64 + blk] = o;
  }
}

// ---------------- K10: GroupNorm normalize (in place on d_out) ----------------
__global__ void k_gn_norm(float* __restrict__ y, const float2* __restrict__ part,
                          const float* __restrict__ gamma, const float* __restrict__ beta) {
  int b = blockIdx.y;
  float s = 0.f, ss = 0.f;
#pragma unroll
  for (int i = 0; i < 64; ++i) { float2 pp = part[b * 64 + i]; s += pp.x; ss += pp.y; }
  const float N = 512.f * 4096.f;
  float mu = s / N;
  float var = ss / N - mu * mu;
  float rstd = rsqrtf(var + 1e-5f);
  size_t base = ((size_t)b << 21) + (size_t)blockIdx.x * 16384;
  float4* p = (float4*)(y + base);
#pragma unroll
  for (int i = 0; i < 16; ++i) {
    int idx = threadIdx.x + i * 256;
    int loc = (int)(blockIdx.x * 16384) + idx * 4;
    int c = loc >> 12;
    float g = gamma[c] * rstd, bt = beta[c];
    float4 v = p[idx];
    v.x = (v.x - mu) * g + bt;
    v.y = (v.y - mu) * g + bt;
    v.z = (v.z - mu) * g + bt;
    v.w = (v.w - mu) * g + bt;
    p[idx] = v;
  }
}

extern "C" void kernel_launch(void* const* d_in, const int* in_sizes, int n_in,
                              void* d_out, int out_size, void* d_ws, size_t ws_size,
                              hipStream_t stream) {
  const float* x     = (const float*)d_in[0];
  // d_in[1] = mask: adds 1e-12 to fp32 logits -> numerically dead; ignored.
  const float* wqkv  = (const float*)d_in[2];
  const float* wout  = (const float*)d_in[3];
  const float* bout  = (const float*)d_in[4];
  const float* gamma = (const float*)d_in[5];
  const float* beta  = (const float*)d_in[6];
  float* y = (float*)d_out;

  char* ws = (char*)d_ws;
  u16*    qkv_b = (u16*)ws;                          // 100,663,296 B  [8][1536][4096] bf16
  u16*    xT    = (u16*)(ws + 100663296);            //  33,554,432 B  [8][4096][512]  bf16
  u16*    outT  = xT;                                //  overlay (xT dead after K3)
  u16*    qT    = (u16*)(ws + 134217728);            //  33,554,432 B  [64][4096][64]  bf16
  u16*    wqkvb = (u16*)(ws + 167772160);            //   1,572,864 B
  u16*    woutb = (u16*)(ws + 169345024);            //     524,288 B
  u16*    ctxT  = (u16*)(ws + 169869312);            //     524,288 B  [64][64][64]    bf16
  float2* part  = (float2*)(ws + 170393600);         //       4,096 B

  k_convert_w<<<1024, 256, 0, stream>>>(wqkv, wout, wqkvb, woutb);
  {
    dim3 g(64, 8, 8);
    k_transpose_x<<<g, 256, 0, stream>>>(x, xT);
  }
  {
    dim3 g(32, 12, 8);
    k_gemm_qkv<<<g, 256, 0, stream>>>(wqkvb, xT, qkv_b);
  }
  k_softmax_q<<<1024, 256, 0, stream>>>(qkv_b, qT);
  k_softmax_k<<<4096, 256, 0, stream>>>(qkv_b);
  k_context<<<64, 256, 0, stream>>>(qkv_b, ctxT);
  {
    dim3 g(32, 64);
    k_attn_out<<<g, 256, 0, stream>>>(qT, ctxT, outT);
  }
  {
    dim3 g(32, 4, 8);
    k_gemm_wout<<<g, 256, 0, stream>>>(woutb, outT, y, bout);
  }
  {
    dim3 g(64, 8);
    k_gn_partial<<<g, 256, 0, stream>>>(y, part);
  }
  {
    dim3 g(128, 8);
    k_gn_norm<<<g, 256, 0, stream>>>(y, part, gamma, beta);
  }
}

// Round 2
// 211.506 us; speedup vs baseline: 1.2233x; 1.2233x over previous
//
#include <hip/hip_runtime.h>
#include <stdint.h>

typedef unsigned short u16;
using f32x4 = __attribute__((ext_vector_type(4))) float;
using s16x8 = __attribute__((ext_vector_type(8))) short;

#define MFMA_BF16(a, b, c) __builtin_amdgcn_mfma_f32_16x16x32_bf16((a), (b), (c), 0, 0, 0)

#define GLOAD_LDS16(gptr, lptr)                                                               \
  __builtin_amdgcn_global_load_lds((const __attribute__((address_space(1))) uint32_t*)(gptr), \
                                   (__attribute__((address_space(3))) uint32_t*)(lptr), 16, 0, 0)

__device__ __forceinline__ u16 f2bf(float f) {
  union { float f; uint32_t u; } v; v.f = f;
  uint32_t r = v.u + 0x7fffu + ((v.u >> 16) & 1u);
  return (u16)(r >> 16);
}
__device__ __forceinline__ float bf2f(u16 h) {
  union { uint32_t u; float f; } v; v.u = ((uint32_t)h) << 16;
  return v.f;
}

// ---------------- K1: convert weights fp32 -> bf16 ----------------
__global__ void k_convert_w(const float* __restrict__ wq, const float* __restrict__ wo,
                            u16* __restrict__ wqb, u16* __restrict__ wob) {
  int i = blockIdx.x * 256 + threadIdx.x;
  const int nq = 1536 * 512 / 4;  // 196608 float4s
  const int no = 512 * 512 / 4;   //  65536 float4s
  if (i < nq) {
    float4 v = ((const float4*)wq)[i];
    u16* o = wqb + i * 4;
    o[0] = f2bf(v.x); o[1] = f2bf(v.y); o[2] = f2bf(v.z); o[3] = f2bf(v.w);
  } else if (i < nq + no) {
    int j = i - nq;
    float4 v = ((const float4*)wo)[j];
    u16* o = wob + j * 4;
    o[0] = f2bf(v.x); o[1] = f2bf(v.y); o[2] = f2bf(v.z); o[3] = f2bf(v.w);
  }
}

// ---------------- K2: x [b][c][t] f32 -> xT [b][t][c] bf16 ----------------
__global__ void k_transpose_x(const float* __restrict__ x, u16* __restrict__ xT) {
  __shared__ u16 tile[64][65];
  int b = blockIdx.z, c0 = blockIdx.y * 64, t0 = blockIdx.x * 64;
  const float* xp = x + ((size_t)b * 512 + c0) * 4096 + t0;
#pragma unroll
  for (int i = 0; i < 16; ++i) {
    int idx = threadIdx.x + i * 256;
    int r = idx >> 6, col = idx & 63;         // r = c, col = t
    tile[r][col] = f2bf(xp[(size_t)r * 4096 + col]);
  }
  __syncthreads();
  u16* op = xT + ((size_t)b * 4096 + t0) * 512 + c0;
#pragma unroll
  for (int i = 0; i < 16; ++i) {
    int idx = threadIdx.x + i * 256;
    int r = idx >> 6, col = idx & 63;         // r = t, col = c
    op[(size_t)r * 512 + col] = tile[col][r];
  }
}

// ---------------- K3: qkv GEMM  C[b][m][n] = sum_k A[m][k]*BT[n][k] ----------------
// A = w_qkv bf16 [1536][512]; BT = xT [b][4096][512]; C = qkv bf16 [b][1536][4096]
__launch_bounds__(256, 2)
__global__ void k_gemm_qkv(const u16* __restrict__ A, const u16* __restrict__ BT,
                           u16* __restrict__ C) {
  __shared__ s16x8 As8[1024];  // [128 rows][8 chunks], swizzled chunk = logical ^ (row&7)
  __shared__ s16x8 Bs8[1024];
  int b = blockIdx.z;
  int m0 = blockIdx.y * 128, n0 = blockIdx.x * 128;
  const u16* Ab = A + (size_t)m0 * 512;
  const u16* Bb = BT + ((size_t)b * 4096 + n0) * 512;
  int tid = threadIdx.x, w = tid >> 6, lane = tid & 63;
  int wm = (w >> 1) * 64, wn = (w & 1) * 64;
  f32x4 acc[4][4] = {};
  for (int kt = 0; kt < 8; ++kt) {
    if (kt) __syncthreads();
#pragma unroll
    for (int it = 0; it < 4; ++it) {
      int L = (w * 4 + it) * 64 + lane;
      int r = L >> 3;
      int lc = (L & 7) ^ (r & 7);
      GLOAD_LDS16(Ab + (size_t)r * 512 + kt * 64 + lc * 8, ((char*)As8) + (w * 4 + it) * 1024);
      GLOAD_LDS16(Bb + (size_t)r * 512 + kt * 64 + lc * 8, ((char*)Bs8) + (w * 4 + it) * 1024);
    }
    asm volatile("s_waitcnt vmcnt(0)");
    __syncthreads();
#pragma unroll
    for (int kk = 0; kk < 2; ++kk) {
      int cb = kk * 4 + (lane >> 4);
      s16x8 af[4], bfr[4];
#pragma unroll
      for (int mi = 0; mi < 4; ++mi) {
        int r = wm + mi * 16 + (lane & 15);
        af[mi] = As8[r * 8 + (cb ^ (r & 7))];
      }
#pragma unroll
      for (int ni = 0; ni < 4; ++ni) {
        int r = wn + ni * 16 + (lane & 15);
        bfr[ni] = Bs8[r * 8 + (cb ^ (r & 7))];
      }
#pragma unroll
      for (int mi = 0; mi < 4; ++mi)
#pragma unroll
        for (int ni = 0; ni < 4; ++ni)
          acc[mi][ni] = MFMA_BF16(af[mi], bfr[ni], acc[mi][ni]);
    }
  }
  u16* Cb = C + ((size_t)b * 1536 + m0) * 4096 + n0;
#pragma unroll
  for (int mi = 0; mi < 4; ++mi)
#pragma unroll
    for (int ni = 0; ni < 4; ++ni)
#pragma unroll
      for (int j = 0; j < 4; ++j) {
        int mm = wm + mi * 16 + (lane >> 4) * 4 + j;
        int nn = wn + ni * 16 + (lane & 15);
        Cb[(size_t)mm * 4096 + nn] = f2bf(acc[mi][ni][j]);
      }
}

// ---------------- K4: q softmax over d (64) -> qT [bh][t][d] bf16, * SCALE ----------------
__global__ void k_softmax_q(const u16* __restrict__ qkv, u16* __restrict__ qT) {
  int idx = blockIdx.x * 256 + threadIdx.x;  // (b,h,t), 262144 total
  int t = idx & 4095;
  int bh = idx >> 12;
  int b = bh >> 3, h = bh & 7;
  const u16* qp = qkv + ((size_t)b * 1536 + h * 64) * 4096 + t;
  float v[64];
  float mx = -1e30f;
#pragma unroll
  for (int d = 0; d < 64; ++d) { v[d] = bf2f(qp[(size_t)d * 4096]); mx = fmaxf(mx, v[d]); }
  float s = 0.f;
#pragma unroll
  for (int d = 0; d < 64; ++d) { v[d] = __expf(v[d] - mx); s += v[d]; }
  float sc = 0.125f / s;  // SCALE = 64^-0.5
  u16* op = qT + ((size_t)bh * 4096 + t) * 64;
#pragma unroll
  for (int d8 = 0; d8 < 8; ++d8) {
    s16x8 o;
#pragma unroll
    for (int j = 0; j < 8; ++j) o[j] = (short)f2bf(v[d8 * 8 + j] * sc);
    ((s16x8*)op)[d8] = o;
  }
}

// ---------------- K5: k softmax over t (4096), in place on qkv's k region ----------------
__global__ void k_softmax_k(u16* __restrict__ kp) {
  int row = blockIdx.x;           // (b, h*64+d): 4096 rows
  int b = row >> 9, rem = row & 511;
  u16* p = kp + ((size_t)b * 1536 + 512 + rem) * 4096;
  int tid = threadIdx.x, lane = tid & 63, w = tid >> 6;
  s16x8 c0 = ((const s16x8*)p)[tid];
  s16x8 c1 = ((const s16x8*)p)[tid + 256];
  float v[16];
#pragma unroll
  for (int j = 0; j < 8; ++j) { v[j] = bf2f((u16)c0[j]); v[8 + j] = bf2f((u16)c1[j]); }
  float mx = -1e30f;
#pragma unroll
  for (int j = 0; j < 16; ++j) mx = fmaxf(mx, v[j]);
#pragma unroll
  for (int off = 32; off; off >>= 1) mx = fmaxf(mx, __shfl_xor(mx, off));
  __shared__ float redm[4], reds[4];
  if (lane == 0) redm[w] = mx;
  __syncthreads();
  mx = fmaxf(fmaxf(redm[0], redm[1]), fmaxf(redm[2], redm[3]));
  float s = 0.f;
#pragma unroll
  for (int j = 0; j < 16; ++j) { v[j] = __expf(v[j] - mx); s += v[j]; }
#pragma unroll
  for (int off = 32; off; off >>= 1) s += __shfl_xor(s, off);
  if (lane == 0) reds[w] = s;
  __syncthreads();
  s = reds[0] + reds[1] + reds[2] + reds[3];
  float inv = 1.f / s;
  s16x8 o0, o1;
#pragma unroll
  for (int j = 0; j < 8; ++j) { o0[j] = (short)f2bf(v[j] * inv); o1[j] = (short)f2bf(v[8 + j] * inv); }
  ((s16x8*)p)[tid] = o0;
  ((s16x8*)p)[tid + 256] = o1;
}

// ---------------- K6a: context partials over 16 n-slices ----------------
// part[bh][s][e][d] = sum_{n in slice s} v[e][n]*k[d][n]   (f32)
__global__ void k_context_part(const u16* __restrict__ qkv, float* __restrict__ part) {
  int s = blockIdx.x;   // 16 slices of 256 time steps
  int bh = blockIdx.y;  // 64
  int b = bh >> 3, h = bh & 7;
  const u16* vbase = qkv + ((size_t)b * 1536 + 1024 + h * 64) * 4096 + s * 256;
  const u16* kbase = qkv + ((size_t)b * 1536 + 512 + h * 64) * 4096 + s * 256;
  int w = threadIdx.x >> 6, lane = threadIdx.x & 63;
  int e0 = w * 16;
  f32x4 acc[4] = {};
  int er = e0 + (lane & 15);
  int nl = (lane >> 4) * 8;
#pragma unroll
  for (int n0 = 0; n0 < 256; n0 += 32) {
    s16x8 a = *(const s16x8*)(vbase + (size_t)er * 4096 + n0 + nl);
#pragma unroll
    for (int ni = 0; ni < 4; ++ni) {
      s16x8 bb = *(const s16x8*)(kbase + (size_t)(ni * 16 + (lane & 15)) * 4096 + n0 + nl);
      acc[ni] = MFMA_BF16(a, bb, acc[ni]);
    }
  }
  float* cp = part + ((size_t)bh * 16 + s) * 4096;
#pragma unroll
  for (int ni = 0; ni < 4; ++ni)
#pragma unroll
    for (int j = 0; j < 4; ++j) {
      int e = e0 + (lane >> 4) * 4 + j;
      int d = ni * 16 + (lane & 15);
      cp[e * 64 + d] = acc[ni][j];
    }
}

// ---------------- K6b: reduce partials -> ctxT bf16 ----------------
__global__ void k_context_reduce(const float* __restrict__ part, u16* __restrict__ ctxT) {
  int idx = blockIdx.x * 256 + threadIdx.x;  // 262144 total
  int bh = idx >> 12, ed = idx & 4095;
  const float* pp = part + (size_t)bh * 16 * 4096 + ed;
  float sum = 0.f;
#pragma unroll
  for (int s = 0; s < 16; ++s) sum += pp[(size_t)s * 4096];
  ctxT[(size_t)bh * 4096 + ed] = f2bf(sum);
}

// ---------------- K7: attn apply  outT[b][t][h*64+e] = sum_d qT[t][d]*ctxT[e][d] ----------
__launch_bounds__(256, 2)
__global__ void k_attn_out(const u16* __restrict__ qT, const u16* __restrict__ ctxT,
                           u16* __restrict__ outT) {
  __shared__ s16x8 Qs[1024];  // [128 t][8 chunks] swizzled
  __shared__ s16x8 Cs[512];   // [64 e][8 chunks] swizzled
  int bh = blockIdx.y;
  int t0 = blockIdx.x * 128;
  int b = bh >> 3, h = bh & 7;
  const u16* qb = qT + ((size_t)bh * 4096 + t0) * 64;
  const u16* cb = ctxT + (size_t)bh * 64 * 64;
  int tid = threadIdx.x, w = tid >> 6, lane = tid & 63;
#pragma unroll
  for (int it = 0; it < 4; ++it) {
    int L = (w * 4 + it) * 64 + lane;
    int r = L >> 3, lc = (L & 7) ^ (r & 7);
    GLOAD_LDS16(qb + (size_t)r * 64 + lc * 8, ((char*)Qs) + (w * 4 + it) * 1024);
  }
#pragma unroll
  for (int it = 0; it < 2; ++it) {
    int L = (w * 2 + it) * 64 + lane;
    int r = L >> 3, lc = (L & 7) ^ (r & 7);
    GLOAD_LDS16(cb + (size_t)r * 64 + lc * 8, ((char*)Cs) + (w * 2 + it) * 1024);
  }
  asm volatile("s_waitcnt vmcnt(0)");
  __syncthreads();
  f32x4 acc[2][4] = {};
#pragma unroll
  for (int kk = 0; kk < 2; ++kk) {
    int cbi = kk * 4 + (lane >> 4);
    s16x8 af[2], bfr[4];
#pragma unroll
    for (int mi = 0; mi < 2; ++mi) {
      int r = w * 32 + mi * 16 + (lane & 15);
      af[mi] = Qs[r * 8 + (cbi ^ (r & 7))];
    }
#pragma unroll
    for (int ni = 0; ni < 4; ++ni) {
      int r = ni * 16 + (lane & 15);
      bfr[ni] = Cs[r * 8 + (cbi ^ (r & 7))];
    }
#pragma unroll
    for (int mi = 0; mi < 2; ++mi)
#pragma unroll
      for (int ni = 0; ni < 4; ++ni)
        acc[mi][ni] = MFMA_BF16(af[mi], bfr[ni], acc[mi][ni]);
  }
  u16* op = outT + ((size_t)b * 4096 + t0) * 512 + h * 64;
#pragma unroll
  for (int mi = 0; mi < 2; ++mi)
#pragma unroll
    for (int ni = 0; ni < 4; ++ni)
#pragma unroll
      for (int j = 0; j < 4; ++j) {
        int t = w * 32 + mi * 16 + (lane >> 4) * 4 + j;
        int e = ni * 16 + (lane & 15);
        op[(size_t)t * 512 + e] = f2bf(acc[mi][ni][j]);
      }
}

// ---------------- K8: w_out GEMM + bias -> y fp32 (d_out) ----------------
// A = w_out bf16 [512][512]; BT = outT [b][4096][512]; y[b][m][n] += b_out[m]
__launch_bounds__(256, 2)
__global__ void k_gemm_wout(const u16* __restrict__ A, const u16* __restrict__ BT,
                            float* __restrict__ Y, const float* __restrict__ bias) {
  __shared__ s16x8 As8[1024];
  __shared__ s16x8 Bs8[1024];
  int b = blockIdx.z;
  int m0 = blockIdx.y * 128, n0 = blockIdx.x * 128;
  const u16* Ab = A + (size_t)m0 * 512;
  const u16* Bb = BT + ((size_t)b * 4096 + n0) * 512;
  int tid = threadIdx.x, w = tid >> 6, lane = tid & 63;
  int wm = (w >> 1) * 64, wn = (w & 1) * 64;
  f32x4 acc[4][4] = {};
  for (int kt = 0; kt < 8; ++kt) {
    if (kt) __syncthreads();
#pragma unroll
    for (int it = 0; it < 4; ++it) {
      int L = (w * 4 + it) * 64 + lane;
      int r = L >> 3;
      int lc = (L & 7) ^ (r & 7);
      GLOAD_LDS16(Ab + (size_t)r * 512 + kt * 64 + lc * 8, ((char*)As8) + (w * 4 + it) * 1024);
      GLOAD_LDS16(Bb + (size_t)r * 512 + kt * 64 + lc * 8, ((char*)Bs8) + (w * 4 + it) * 1024);
    }
    asm volatile("s_waitcnt vmcnt(0)");
    __syncthreads();
#pragma unroll
    for (int kk = 0; kk < 2; ++kk) {
      int cb = kk * 4 + (lane >> 4);
      s16x8 af[4], bfr[4];
#pragma unroll
      for (int mi = 0; mi < 4; ++mi) {
        int r = wm + mi * 16 + (lane & 15);
        af[mi] = As8[r * 8 + (cb ^ (r & 7))];
      }
#pragma unroll
      for (int ni = 0; ni < 4; ++ni) {
        int r = wn + ni * 16 + (lane & 15);
        bfr[ni] = Bs8[r * 8 + (cb ^ (r & 7))];
      }
#pragma unroll
      for (int mi = 0; mi < 4; ++mi)
#pragma unroll
        for (int ni = 0; ni < 4; ++ni)
          acc[mi][ni] = MFMA_BF16(af[mi], bfr[ni], acc[mi][ni]);
    }
  }
  float* Yb = Y + ((size_t)b * 512 + m0) * 4096 + n0;
#pragma unroll
  for (int mi = 0; mi < 4; ++mi)
#pragma unroll
    for (int j = 0; j < 4; ++j) {
      int mm = wm + mi * 16 + (lane >> 4) * 4 + j;
      float bo = bias[m0 + mm];
#pragma unroll
      for (int ni = 0; ni < 4; ++ni) {
        int nn = wn + ni * 16 + (lane & 15);
        Yb[(size_t)mm * 4096 + nn] = acc[mi][ni][j] + bo;
      }
    }
}

// ---------------- K9: GroupNorm partial sums per batch ----------------
__global__ void k_gn_partial(const float* __restrict__ y, float2* __restrict__ part) {
  int b = blockIdx.y, blk = blockIdx.x;  // 64 blocks per batch, 32768 elems each
  const float4* p = (const float4*)(y + ((size_t)b << 21) + (size_t)blk * 32768);
  int tid = threadIdx.x, lane = tid & 63, w = tid >> 6;
  float s = 0.f, ss = 0.f;
#pragma unroll
  for (int i = 0; i < 32; ++i) {
    float4 v = p[tid + i * 256];
    s += v.x + v.y + v.z + v.w;
    ss += v.x * v.x + v.y * v.y + v.z * v.z + v.w * v.w;
  }
#pragma unroll
  for (int off = 32; off; off >>= 1) { s += __shfl_xor(s, off); ss += __shfl_xor(ss, off); }
  __shared__ float sr[4], ssr[4];
  if (lane == 0) { sr[w] = s; ssr[w] = ss; }
  __syncthreads();
  if (tid == 0) {
    float2 o;
    o.x = sr[0] + sr[1] + sr[2] + sr[3];
    o.y = ssr[0] + ssr[1] + ssr[2] + ssr[3];
    part[b * 64 + blk] = o;
  }
}

// ---------------- K10: GroupNorm normalize (in place on d_out) ----------------
__global__ void k_gn_norm(float* __restrict__ y, const float2* __restrict__ part,
                          const float* __restrict__ gamma, const float* __restrict__ beta) {
  int b = blockIdx.y;
  float s = 0.f, ss = 0.f;
#pragma unroll
  for (int i = 0; i < 64; ++i) { float2 pp = part[b * 64 + i]; s += pp.x; ss += pp.y; }
  const float N = 512.f * 4096.f;
  float mu = s / N;
  float var = ss / N - mu * mu;
  float rstd = rsqrtf(var + 1e-5f);
  size_t base = ((size_t)b << 21) + (size_t)blockIdx.x * 16384;
  float4* p = (float4*)(y + base);
#pragma unroll
  for (int i = 0; i < 16; ++i) {
    int idx = threadIdx.x + i * 256;
    int loc = (int)(blockIdx.x * 16384) + idx * 4;
    int c = loc >> 12;
    float g = gamma[c] * rstd, bt = beta[c];
    float4 v = p[idx];
    v.x = (v.x - mu) * g + bt;
    v.y = (v.y - mu) * g + bt;
    v.z = (v.z - mu) * g + bt;
    v.w = (v.w - mu) * g + bt;
    p[idx] = v;
  }
}

extern "C" void kernel_launch(void* const* d_in, const int* in_sizes, int n_in,
                              void* d_out, int out_size, void* d_ws, size_t ws_size,
                              hipStream_t stream) {
  const float* x     = (const float*)d_in[0];
  // d_in[1] = mask: adds 1e-12 to fp32 logits -> numerically dead; ignored.
  const float* wqkv  = (const float*)d_in[2];
  const float* wout  = (const float*)d_in[3];
  const float* bout  = (const float*)d_in[4];
  const float* gamma = (const float*)d_in[5];
  const float* beta  = (const float*)d_in[6];
  float* y = (float*)d_out;

  char* ws = (char*)d_ws;
  u16*    qkv_b = (u16*)ws;                          // 100,663,296 B  [8][1536][4096] bf16
  u16*    xT    = (u16*)(ws + 100663296);            //  33,554,432 B  [8][4096][512]  bf16
  u16*    outT  = xT;                                //  overlay (xT dead after K3)
  float*  ctxp  = (float*)(ws + 100663296);          //  overlay too: 16,777,216 B [64][16][64][64] f32
                                                     //  (lives only between K3 and K7)
  u16*    qT    = (u16*)(ws + 134217728);            //  33,554,432 B  [64][4096][64]  bf16
  u16*    wqkvb = (u16*)(ws + 167772160);            //   1,572,864 B
  u16*    woutb = (u16*)(ws + 169345024);            //     524,288 B
  u16*    ctxT  = (u16*)(ws + 169869312);            //     524,288 B  [64][64][64]    bf16
  float2* part  = (float2*)(ws + 170393600);         //       4,096 B

  k_convert_w<<<1024, 256, 0, stream>>>(wqkv, wout, wqkvb, woutb);
  {
    dim3 g(64, 8, 8);
    k_transpose_x<<<g, 256, 0, stream>>>(x, xT);
  }
  {
    dim3 g(32, 12, 8);
    k_gemm_qkv<<<g, 256, 0, stream>>>(wqkvb, xT, qkv_b);
  }
  k_softmax_q<<<1024, 256, 0, stream>>>(qkv_b, qT);
  k_softmax_k<<<4096, 256, 0, stream>>>(qkv_b);
  {
    dim3 g(16, 64);
    k_context_part<<<g, 256, 0, stream>>>(qkv_b, ctxp);
  }
  k_context_reduce<<<1024, 256, 0, stream>>>(ctxp, ctxT);
  {
    dim3 g(32, 64);
    k_attn_out<<<g, 256, 0, stream>>>(qT, ctxT, outT);
  }
  {
    dim3 g(32, 4, 8);
    k_gemm_wout<<<g, 256, 0, stream>>>(woutb, outT, y, bout);
  }
  {
    dim3 g(64, 8);
    k_gn_partial<<<g, 256, 0, stream>>>(y, part);
  }
  {
    dim3 g(128, 8);
    k_gn_norm<<<g, 256, 0, stream>>>(y, part, gamma, beta);
  }
}

// Round 3
// 183.289 us; speedup vs baseline: 1.4116x; 1.1539x over previous
//
#include <hip/hip_runtime.h>
#include <stdint.h>

typedef unsigned short u16;
using f32x4 = __attribute__((ext_vector_type(4))) float;
using s16x8 = __attribute__((ext_vector_type(8))) short;

#define MFMA_BF16(a, b, c) __builtin_amdgcn_mfma_f32_16x16x32_bf16((a), (b), (c), 0, 0, 0)

#define GLOAD_LDS16(gptr, lptr)                                                               \
  __builtin_amdgcn_global_load_lds((const __attribute__((address_space(1))) uint32_t*)(gptr), \
                                   (__attribute__((address_space(3))) uint32_t*)(lptr), 16, 0, 0)

__device__ __forceinline__ u16 f2bf(float f) {
  union { float f; uint32_t u; } v; v.f = f;
  uint32_t r = v.u + 0x7fffu + ((v.u >> 16) & 1u);
  return (u16)(r >> 16);
}
__device__ __forceinline__ float bf2f(u16 h) {
  union { uint32_t u; float f; } v; v.u = ((uint32_t)h) << 16;
  return v.f;
}

// ---------------- K1: convert weights fp32 -> bf16 ----------------
__global__ void k_convert_w(const float* __restrict__ wq, const float* __restrict__ wo,
                            u16* __restrict__ wqb, u16* __restrict__ wob) {
  int i = blockIdx.x * 256 + threadIdx.x;
  const int nq = 1536 * 512 / 4;
  const int no = 512 * 512 / 4;
  if (i < nq) {
    float4 v = ((const float4*)wq)[i];
    u16* o = wqb + i * 4;
    o[0] = f2bf(v.x); o[1] = f2bf(v.y); o[2] = f2bf(v.z); o[3] = f2bf(v.w);
  } else if (i < nq + no) {
    int j = i - nq;
    float4 v = ((const float4*)wo)[j];
    u16* o = wob + j * 4;
    o[0] = f2bf(v.x); o[1] = f2bf(v.y); o[2] = f2bf(v.z); o[3] = f2bf(v.w);
  }
}

// ---------------- K2: x [b][c][t] f32 -> xT [b][t][c] bf16 ----------------
__global__ void k_transpose_x(const float* __restrict__ x, u16* __restrict__ xT) {
  __shared__ u16 tile[64][65];
  int b = blockIdx.z, c0 = blockIdx.y * 64, t0 = blockIdx.x * 64;
  const float* xp = x + ((size_t)b * 512 + c0) * 4096 + t0;
#pragma unroll
  for (int i = 0; i < 16; ++i) {
    int idx = threadIdx.x + i * 256;
    int r = idx >> 6, col = idx & 63;
    tile[r][col] = f2bf(xp[(size_t)r * 4096 + col]);
  }
  __syncthreads();
  u16* op = xT + ((size_t)b * 4096 + t0) * 512 + c0;
#pragma unroll
  for (int i = 0; i < 16; ++i) {
    int idx = threadIdx.x + i * 256;
    int r = idx >> 6, col = idx & 63;
    op[(size_t)r * 512 + col] = tile[col][r];
  }
}

// ---------------- K3: qkv GEMM with fused q-softmax epilogue ----------------
// A = w_qkv bf16 [1536][512]; BT = xT [b][4096][512]
// m-tiles 0..3 (q): softmax over d, *SCALE, write qT [bh][t][64]
// m-tiles 4..11 (k,v): write qkv_b [b][1536][4096] (q region left unused)
__launch_bounds__(256, 2)
__global__ void k_gemm_qkv(const u16* __restrict__ A, const u16* __restrict__ BT,
                           u16* __restrict__ C, u16* __restrict__ qT) {
  __shared__ s16x8 As8[1024];  // [128 rows][8 chunks], chunk swizzle = logical ^ (row&7)
  __shared__ s16x8 Bs8[1024];
  int b = blockIdx.z;
  int m0 = blockIdx.y * 128, n0 = blockIdx.x * 128;
  const u16* Ab = A + (size_t)m0 * 512;
  const u16* Bb = BT + ((size_t)b * 4096 + n0) * 512;
  int tid = threadIdx.x, w = tid >> 6, lane = tid & 63;
  int wm = (w >> 1) * 64, wn = (w & 1) * 64;
  f32x4 acc[4][4] = {};
  for (int kt = 0; kt < 8; ++kt) {
    if (kt) __syncthreads();
#pragma unroll
    for (int it = 0; it < 4; ++it) {
      int L = (w * 4 + it) * 64 + lane;
      int r = L >> 3;
      int lc = (L & 7) ^ (r & 7);
      GLOAD_LDS16(Ab + (size_t)r * 512 + kt * 64 + lc * 8, ((char*)As8) + (w * 4 + it) * 1024);
      GLOAD_LDS16(Bb + (size_t)r * 512 + kt * 64 + lc * 8, ((char*)Bs8) + (w * 4 + it) * 1024);
    }
    asm volatile("s_waitcnt vmcnt(0)");
    __syncthreads();
#pragma unroll
    for (int kk = 0; kk < 2; ++kk) {
      int cb = kk * 4 + (lane >> 4);
      s16x8 af[4], bfr[4];
#pragma unroll
      for (int mi = 0; mi < 4; ++mi) {
        int r = wm + mi * 16 + (lane & 15);
        af[mi] = As8[r * 8 + (cb ^ (r & 7))];
      }
#pragma unroll
      for (int ni = 0; ni < 4; ++ni) {
        int r = wn + ni * 16 + (lane & 15);
        bfr[ni] = Bs8[r * 8 + (cb ^ (r & 7))];
      }
#pragma unroll
      for (int mi = 0; mi < 4; ++mi)
#pragma unroll
        for (int ni = 0; ni < 4; ++ni)
          acc[mi][ni] = MFMA_BF16(af[mi], bfr[ni], acc[mi][ni]);
    }
  }
  if (blockIdx.y < 4) {
    // q region: this warp's 64 m-rows == one full head's d range.
    int head = (m0 >> 6) + (wm >> 6);
    int bh = b * 8 + head;
#pragma unroll
    for (int ni = 0; ni < 4; ++ni) {
      float mx = -1e30f;
#pragma unroll
      for (int mi = 0; mi < 4; ++mi)
#pragma unroll
        for (int j = 0; j < 4; ++j) mx = fmaxf(mx, acc[mi][ni][j]);
      mx = fmaxf(mx, __shfl_xor(mx, 16));
      mx = fmaxf(mx, __shfl_xor(mx, 32));
      float e[4][4];
      float s = 0.f;
#pragma unroll
      for (int mi = 0; mi < 4; ++mi)
#pragma unroll
        for (int j = 0; j < 4; ++j) { e[mi][j] = __expf(acc[mi][ni][j] - mx); s += e[mi][j]; }
      s += __shfl_xor(s, 16);
      s += __shfl_xor(s, 32);
      float sc = 0.125f / s;  // SCALE = 64^-0.5
      int t = n0 + wn + ni * 16 + (lane & 15);
      u16* op = qT + ((size_t)bh * 4096 + t) * 64 + (lane >> 4) * 4;
#pragma unroll
      for (int mi = 0; mi < 4; ++mi) {
        union { u16 u[4]; uint2 v; } pk;
#pragma unroll
        for (int j = 0; j < 4; ++j) pk.u[j] = f2bf(e[mi][j] * sc);
        *(uint2*)(op + mi * 16) = pk.v;
      }
    }
  } else {
    u16* Cb = C + ((size_t)b * 1536 + m0) * 4096 + n0;
#pragma unroll
    for (int mi = 0; mi < 4; ++mi)
#pragma unroll
      for (int ni = 0; ni < 4; ++ni)
#pragma unroll
        for (int j = 0; j < 4; ++j) {
          int mm = wm + mi * 16 + (lane >> 4) * 4 + j;
          int nn = wn + ni * 16 + (lane & 15);
          Cb[(size_t)mm * 4096 + nn] = f2bf(acc[mi][ni][j]);
        }
  }
}

// ---------------- K5: k softmax over t (4096), in place on qkv's k region ----------------
__global__ void k_softmax_k(u16* __restrict__ kp) {
  int row = blockIdx.x;  // (b, h*64+d): 4096 rows
  int b = row >> 9, rem = row & 511;
  u16* p = kp + ((size_t)b * 1536 + 512 + rem) * 4096;
  int tid = threadIdx.x, lane = tid & 63, w = tid >> 6;
  s16x8 c0 = ((const s16x8*)p)[tid];
  s16x8 c1 = ((const s16x8*)p)[tid + 256];
  float v[16];
#pragma unroll
  for (int j = 0; j < 8; ++j) { v[j] = bf2f((u16)c0[j]); v[8 + j] = bf2f((u16)c1[j]); }
  float mx = -1e30f;
#pragma unroll
  for (int j = 0; j < 16; ++j) mx = fmaxf(mx, v[j]);
#pragma unroll
  for (int off = 32; off; off >>= 1) mx = fmaxf(mx, __shfl_xor(mx, off));
  __shared__ float redm[4], reds[4];
  if (lane == 0) redm[w] = mx;
  __syncthreads();
  mx = fmaxf(fmaxf(redm[0], redm[1]), fmaxf(redm[2], redm[3]));
  float s = 0.f;
#pragma unroll
  for (int j = 0; j < 16; ++j) { v[j] = __expf(v[j] - mx); s += v[j]; }
#pragma unroll
  for (int off = 32; off; off >>= 1) s += __shfl_xor(s, off);
  if (lane == 0) reds[w] = s;
  __syncthreads();
  s = reds[0] + reds[1] + reds[2] + reds[3];
  float inv = 1.f / s;
  s16x8 o0, o1;
#pragma unroll
  for (int j = 0; j < 8; ++j) { o0[j] = (short)f2bf(v[j] * inv); o1[j] = (short)f2bf(v[8 + j] * inv); }
  ((s16x8*)p)[tid] = o0;
  ((s16x8*)p)[tid + 256] = o1;
}

// ---------------- K6a: context partials over 16 n-slices ----------------
__global__ void k_context_part(const u16* __restrict__ qkv, float* __restrict__ part) {
  int s = blockIdx.x;   // 16 slices of 256 time steps
  int bh = blockIdx.y;  // 64
  int b = bh >> 3, h = bh & 7;
  const u16* vbase = qkv + ((size_t)b * 1536 + 1024 + h * 64) * 4096 + s * 256;
  const u16* kbase = qkv + ((size_t)b * 1536 + 512 + h * 64) * 4096 + s * 256;
  int w = threadIdx.x >> 6, lane = threadIdx.x & 63;
  int e0 = w * 16;
  f32x4 acc[4] = {};
  int er = e0 + (lane & 15);
  int nl = (lane >> 4) * 8;
#pragma unroll
  for (int n0 = 0; n0 < 256; n0 += 32) {
    s16x8 a = *(const s16x8*)(vbase + (size_t)er * 4096 + n0 + nl);
#pragma unroll
    for (int ni = 0; ni < 4; ++ni) {
      s16x8 bb = *(const s16x8*)(kbase + (size_t)(ni * 16 + (lane & 15)) * 4096 + n0 + nl);
      acc[ni] = MFMA_BF16(a, bb, acc[ni]);
    }
  }
  float* cp = part + ((size_t)bh * 16 + s) * 4096;
#pragma unroll
  for (int ni = 0; ni < 4; ++ni)
#pragma unroll
    for (int j = 0; j < 4; ++j) {
      int e = e0 + (lane >> 4) * 4 + j;
      int d = ni * 16 + (lane & 15);
      cp[e * 64 + d] = acc[ni][j];
    }
}

// ---------------- K6b: reduce partials -> ctxT bf16 ----------------
__global__ void k_context_reduce(const float* __restrict__ part, u16* __restrict__ ctxT) {
  int idx = blockIdx.x * 256 + threadIdx.x;  // 262144 total
  int bh = idx >> 12, ed = idx & 4095;
  const float* pp = part + (size_t)bh * 16 * 4096 + ed;
  float sum = 0.f;
#pragma unroll
  for (int s = 0; s < 16; ++s) sum += pp[(size_t)s * 4096];
  ctxT[(size_t)bh * 4096 + ed] = f2bf(sum);
}

// ---------------- K7: attn apply  outT[b][t][h*64+e] = sum_d qT[t][d]*ctxT[e][d] ----------
__launch_bounds__(256, 2)
__global__ void k_attn_out(const u16* __restrict__ qT, const u16* __restrict__ ctxT,
                           u16* __restrict__ outT) {
  __shared__ s16x8 Qs[1024];  // [128 t][8 chunks] swizzled
  __shared__ s16x8 Cs[512];   // [64 e][8 chunks] swizzled
  int bh = blockIdx.y;
  int t0 = blockIdx.x * 128;
  int b = bh >> 3, h = bh & 7;
  const u16* qb = qT + ((size_t)bh * 4096 + t0) * 64;
  const u16* cb = ctxT + (size_t)bh * 64 * 64;
  int tid = threadIdx.x, w = tid >> 6, lane = tid & 63;
#pragma unroll
  for (int it = 0; it < 4; ++it) {
    int L = (w * 4 + it) * 64 + lane;
    int r = L >> 3, lc = (L & 7) ^ (r & 7);
    GLOAD_LDS16(qb + (size_t)r * 64 + lc * 8, ((char*)Qs) + (w * 4 + it) * 1024);
  }
#pragma unroll
  for (int it = 0; it < 2; ++it) {
    int L = (w * 2 + it) * 64 + lane;
    int r = L >> 3, lc = (L & 7) ^ (r & 7);
    GLOAD_LDS16(cb + (size_t)r * 64 + lc * 8, ((char*)Cs) + (w * 2 + it) * 1024);
  }
  asm volatile("s_waitcnt vmcnt(0)");
  __syncthreads();
  f32x4 acc[2][4] = {};
#pragma unroll
  for (int kk = 0; kk < 2; ++kk) {
    int cbi = kk * 4 + (lane >> 4);
    s16x8 af[2], bfr[4];
#pragma unroll
    for (int mi = 0; mi < 2; ++mi) {
      int r = w * 32 + mi * 16 + (lane & 15);
      af[mi] = Qs[r * 8 + (cbi ^ (r & 7))];
    }
#pragma unroll
    for (int ni = 0; ni < 4; ++ni) {
      int r = ni * 16 + (lane & 15);
      bfr[ni] = Cs[r * 8 + (cbi ^ (r & 7))];
    }
#pragma unroll
    for (int mi = 0; mi < 2; ++mi)
#pragma unroll
      for (int ni = 0; ni < 4; ++ni)
        acc[mi][ni] = MFMA_BF16(af[mi], bfr[ni], acc[mi][ni]);
  }
  u16* op = outT + ((size_t)b * 4096 + t0) * 512 + h * 64;
#pragma unroll
  for (int mi = 0; mi < 2; ++mi)
#pragma unroll
    for (int ni = 0; ni < 4; ++ni)
#pragma unroll
      for (int j = 0; j < 4; ++j) {
        int t = w * 32 + mi * 16 + (lane >> 4) * 4 + j;
        int e = ni * 16 + (lane & 15);
        op[(size_t)t * 512 + e] = f2bf(acc[mi][ni][j]);
      }
}

// ---------------- K8: w_out GEMM + bias -> ybf bf16, fused GN partial sums ----------------
// A = w_out bf16 [512][512]; BT = outT [b][4096][512]
__launch_bounds__(256, 2)
__global__ void k_gemm_wout(const u16* __restrict__ A, const u16* __restrict__ BT,
                            u16* __restrict__ Ybf, const float* __restrict__ bias,
                            float2* __restrict__ part2) {
  __shared__ s16x8 As8[1024];
  __shared__ s16x8 Bs8[1024];
  int b = blockIdx.z;
  int m0 = blockIdx.y * 128, n0 = blockIdx.x * 128;
  const u16* Ab = A + (size_t)m0 * 512;
  const u16* Bb = BT + ((size_t)b * 4096 + n0) * 512;
  int tid = threadIdx.x, w = tid >> 6, lane = tid & 63;
  int wm = (w >> 1) * 64, wn = (w & 1) * 64;
  f32x4 acc[4][4] = {};
  for (int kt = 0; kt < 8; ++kt) {
    if (kt) __syncthreads();
#pragma unroll
    for (int it = 0; it < 4; ++it) {
      int L = (w * 4 + it) * 64 + lane;
      int r = L >> 3;
      int lc = (L & 7) ^ (r & 7);
      GLOAD_LDS16(Ab + (size_t)r * 512 + kt * 64 + lc * 8, ((char*)As8) + (w * 4 + it) * 1024);
      GLOAD_LDS16(Bb + (size_t)r * 512 + kt * 64 + lc * 8, ((char*)Bs8) + (w * 4 + it) * 1024);
    }
    asm volatile("s_waitcnt vmcnt(0)");
    __syncthreads();
#pragma unroll
    for (int kk = 0; kk < 2; ++kk) {
      int cb = kk * 4 + (lane >> 4);
      s16x8 af[4], bfr[4];
#pragma unroll
      for (int mi = 0; mi < 4; ++mi) {
        int r = wm + mi * 16 + (lane & 15);
        af[mi] = As8[r * 8 + (cb ^ (r & 7))];
      }
#pragma unroll
      for (int ni = 0; ni < 4; ++ni) {
        int r = wn + ni * 16 + (lane & 15);
        bfr[ni] = Bs8[r * 8 + (cb ^ (r & 7))];
      }
#pragma unroll
      for (int mi = 0; mi < 4; ++mi)
#pragma unroll
        for (int ni = 0; ni < 4; ++ni)
          acc[mi][ni] = MFMA_BF16(af[mi], bfr[ni], acc[mi][ni]);
    }
  }
  u16* Yb = Ybf + ((size_t)b * 512 + m0) * 4096 + n0;
  float sm = 0.f, ssm = 0.f;
#pragma unroll
  for (int mi = 0; mi < 4; ++mi)
#pragma unroll
    for (int j = 0; j < 4; ++j) {
      int mm = wm + mi * 16 + (lane >> 4) * 4 + j;
      float bo = bias[m0 + mm];
#pragma unroll
      for (int ni = 0; ni < 4; ++ni) {
        int nn = wn + ni * 16 + (lane & 15);
        float vv = acc[mi][ni][j] + bo;
        sm += vv;
        ssm += vv * vv;
        Yb[(size_t)mm * 4096 + nn] = f2bf(vv);
      }
    }
  // block reduction of GN partial sums (deterministic fixed order)
#pragma unroll
  for (int off = 32; off; off >>= 1) { sm += __shfl_xor(sm, off); ssm += __shfl_xor(ssm, off); }
  __shared__ float sr[4], ssr[4];
  if (lane == 0) { sr[w] = sm; ssr[w] = ssm; }
  __syncthreads();
  if (tid == 0) {
    float2 o;
    o.x = sr[0] + sr[1] + sr[2] + sr[3];
    o.y = ssr[0] + ssr[1] + ssr[2] + ssr[3];
    part2[((size_t)b * 4 + blockIdx.y) * 32 + blockIdx.x] = o;
  }
}

// ---------------- K10: GroupNorm normalize  ybf bf16 -> d_out f32 ----------------
__global__ void k_gn_norm(const u16* __restrict__ ybf, float* __restrict__ y,
                          const float2* __restrict__ part2,
                          const float* __restrict__ gamma, const float* __restrict__ beta) {
  int b = blockIdx.y;
  float s = 0.f, ss = 0.f;
#pragma unroll 8
  for (int i = 0; i < 128; ++i) { float2 pp = part2[b * 128 + i]; s += pp.x; ss += pp.y; }
  const float N = 512.f * 4096.f;
  float mu = s / N;
  float var = ss / N - mu * mu;
  float rstd = rsqrtf(var + 1e-5f);
  size_t base = ((size_t)b << 21) + (size_t)blockIdx.x * 16384;
  const s16x8* ip = (const s16x8*)(ybf + base);
  float4* opf = (float4*)(y + base);
#pragma unroll
  for (int i = 0; i < 8; ++i) {
    int idx = threadIdx.x + i * 256;
    int loc = (int)(blockIdx.x * 16384) + idx * 8;
    int c = loc >> 12;
    float g = gamma[c] * rstd, bt = beta[c];
    s16x8 v = ip[idx];
    float4 o0, o1;
    o0.x = (bf2f((u16)v[0]) - mu) * g + bt;
    o0.y = (bf2f((u16)v[1]) - mu) * g + bt;
    o0.z = (bf2f((u16)v[2]) - mu) * g + bt;
    o0.w = (bf2f((u16)v[3]) - mu) * g + bt;
    o1.x = (bf2f((u16)v[4]) - mu) * g + bt;
    o1.y = (bf2f((u16)v[5]) - mu) * g + bt;
    o1.z = (bf2f((u16)v[6]) - mu) * g + bt;
    o1.w = (bf2f((u16)v[7]) - mu) * g + bt;
    opf[idx * 2] = o0;
    opf[idx * 2 + 1] = o1;
  }
}

extern "C" void kernel_launch(void* const* d_in, const int* in_sizes, int n_in,
                              void* d_out, int out_size, void* d_ws, size_t ws_size,
                              hipStream_t stream) {
  const float* x     = (const float*)d_in[0];
  // d_in[1] = mask: adds 1e-12 to fp32 logits -> numerically dead; ignored.
  const float* wqkv  = (const float*)d_in[2];
  const float* wout  = (const float*)d_in[3];
  const float* bout  = (const float*)d_in[4];
  const float* gamma = (const float*)d_in[5];
  const float* beta  = (const float*)d_in[6];
  float* y = (float*)d_out;

  char* ws = (char*)d_ws;
  u16*    qkv_b = (u16*)ws;                   // 100,663,296 B [8][1536][4096] bf16 (q region unused)
  u16*    ybf   = (u16*)ws;                   //  overlay: 33,554,432 B [8][512][4096] bf16 (after ctx)
  u16*    xT    = (u16*)(ws + 100663296);     //  33,554,432 B [8][4096][512] bf16
  u16*    outT  = xT;                         //  overlay (xT dead after K3)
  float*  ctxp  = (float*)(ws + 100663296);   //  (unused overlap note: ctxp lives below instead)
  u16*    qT    = (u16*)(ws + 134217728);     //  33,554,432 B [64][4096][64] bf16
  u16*    wqkvb = (u16*)(ws + 167772160);     //   1,572,864 B
  u16*    woutb = (u16*)(ws + 169345024);     //     524,288 B
  u16*    ctxT  = (u16*)(ws + 169869312);     //     524,288 B [64][64][64] bf16
  float2* part2 = (float2*)(ws + 170393600);  //       8,192 B (1024 float2)
  float*  ctxpp = (float*)(ws + 170401792);   //  16,777,216 B [64][16][64][64] f32

  k_convert_w<<<1024, 256, 0, stream>>>(wqkv, wout, wqkvb, woutb);
  {
    dim3 g(64, 8, 8);
    k_transpose_x<<<g, 256, 0, stream>>>(x, xT);
  }
  {
    dim3 g(32, 12, 8);
    k_gemm_qkv<<<g, 256, 0, stream>>>(wqkvb, xT, qkv_b, qT);
  }
  k_softmax_k<<<4096, 256, 0, stream>>>(qkv_b);
  {
    dim3 g(16, 64);
    k_context_part<<<g, 256, 0, stream>>>(qkv_b, ctxpp);
  }
  k_context_reduce<<<1024, 256, 0, stream>>>(ctxpp, ctxT);
  {
    dim3 g(32, 64);
    k_attn_out<<<g, 256, 0, stream>>>(qT, ctxT, outT);
  }
  {
    dim3 g(32, 4, 8);
    k_gemm_wout<<<g, 256, 0, stream>>>(woutb, outT, ybf, bout, part2);
  }
  {
    dim3 g(128, 8);
    k_gn_norm<<<g, 256, 0, stream>>>(ybf, y, part2, gamma, beta);
  }
}

// Round 4
// 179.348 us; speedup vs baseline: 1.4426x; 1.0220x over previous
//
#include <hip/hip_runtime.h>
#include <stdint.h>

typedef unsigned short u16;
using f32x4 = __attribute__((ext_vector_type(4))) float;
using s16x8 = __attribute__((ext_vector_type(8))) short;

#define MFMA_BF16(a, b, c) __builtin_amdgcn_mfma_f32_16x16x32_bf16((a), (b), (c), 0, 0, 0)

#define GLOAD_LDS16(gptr, lptr)                                                               \
  __builtin_amdgcn_global_load_lds((const __attribute__((address_space(1))) uint32_t*)(gptr), \
                                   (__attribute__((address_space(3))) uint32_t*)(lptr), 16, 0, 0)

__device__ __forceinline__ u16 f2bf(float f) {
  union { float f; uint32_t u; } v; v.f = f;
  uint32_t r = v.u + 0x7fffu + ((v.u >> 16) & 1u);
  return (u16)(r >> 16);
}
__device__ __forceinline__ float bf2f(u16 h) {
  union { uint32_t u; float f; } v; v.u = ((uint32_t)h) << 16;
  return v.f;
}

// ---------------- K1: convert weights fp32 -> bf16 ----------------
__global__ void k_convert_w(const float* __restrict__ wq, const float* __restrict__ wo,
                            u16* __restrict__ wqb, u16* __restrict__ wob) {
  int i = blockIdx.x * 256 + threadIdx.x;
  const int nq = 1536 * 512 / 4;
  const int no = 512 * 512 / 4;
  if (i < nq) {
    float4 v = ((const float4*)wq)[i];
    u16* o = wqb + i * 4;
    o[0] = f2bf(v.x); o[1] = f2bf(v.y); o[2] = f2bf(v.z); o[3] = f2bf(v.w);
  } else if (i < nq + no) {
    int j = i - nq;
    float4 v = ((const float4*)wo)[j];
    u16* o = wob + j * 4;
    o[0] = f2bf(v.x); o[1] = f2bf(v.y); o[2] = f2bf(v.z); o[3] = f2bf(v.w);
  }
}

// ---------------- K2: x [b][c][t] f32 -> xT [b][t][c] bf16 ----------------
__global__ void k_transpose_x(const float* __restrict__ x, u16* __restrict__ xT) {
  __shared__ u16 tile[64][65];
  int b = blockIdx.z, c0 = blockIdx.y * 64, t0 = blockIdx.x * 64;
  const float* xp = x + ((size_t)b * 512 + c0) * 4096 + t0;
#pragma unroll
  for (int i = 0; i < 16; ++i) {
    int idx = threadIdx.x + i * 256;
    int r = idx >> 6, col = idx & 63;
    tile[r][col] = f2bf(xp[(size_t)r * 4096 + col]);
  }
  __syncthreads();
  u16* op = xT + ((size_t)b * 4096 + t0) * 512 + c0;
#pragma unroll
  for (int i = 0; i < 16; ++i) {
    int idx = threadIdx.x + i * 256;
    int r = idx >> 6, col = idx & 63;
    op[(size_t)r * 512 + col] = tile[col][r];
  }
}

// ============ pipelined GEMM core (BM=128, BN=256, BK=64, 512 thr, 3 LDS bufs) ============
// LDS layout per K-tile buffer: rows x 8 chunks of 8 bf16; physical chunk = logical ^ (row&7).
// Schedule per K-tile: sched_barrier; vmcnt(6); s_barrier; phaseA{12 ds_read | 3 gload |
// lgkmcnt(0)+sched_barrier | 16 MFMA}; phaseB{4 ds_read | 3 gload | lgkmcnt(0)+SB | 16 MFMA}.
// Prefetch of tile k+2 -> buf (k+2)%3 (holds tile k-1, fully consumed before this iteration's
// barrier => WAR-safe). vmcnt(6) leaves exactly tile k+1's 6 loads in flight => RAW-safe (FIFO).
#define GEMM_CORE_512(Ab, Bb)                                                                  \
  s16x8* Asl = (s16x8*)lds;               /* 3 * 1024 * 16B = 49152 */                         \
  s16x8* Bsl = (s16x8*)(lds + 49152);     /* 3 * 2048 * 16B = 98304 */                         \
  int tid = threadIdx.x;                                                                       \
  int w = tid >> 6, lane = tid & 63;                                                           \
  int wr = w >> 2, wc = w & 3;                                                                 \
  int hi = lane >> 4, lo = lane & 15;                                                          \
  int rA = tid >> 3, pc = tid & 7;                                                             \
  size_t srcA = (size_t)rA * 512 + (size_t)(pc ^ (rA & 7)) * 8;                                \
  f32x4 acc[4][4] = {};                                                                        \
  /* prologue: stage K-tiles 0,1 into bufs 0,1 (6 loads each, order A0 A1 B0 B1 B2 B3) */      \
  {                                                                                            \
    GLOAD_LDS16(Ab + srcA,          ((char*)Asl) + w * 1024);                                  \
    GLOAD_LDS16(Ab + srcA + 32768,  ((char*)Asl) + 8192 + w * 1024);                           \
    GLOAD_LDS16(Bb + srcA,          ((char*)Bsl) + w * 1024);                                  \
    GLOAD_LDS16(Bb + srcA + 32768,  ((char*)Bsl) + 8192 + w * 1024);                           \
    GLOAD_LDS16(Bb + srcA + 65536,  ((char*)Bsl) + 16384 + w * 1024);                          \
    GLOAD_LDS16(Bb + srcA + 98304,  ((char*)Bsl) + 24576 + w * 1024);                          \
    GLOAD_LDS16(Ab + srcA + 64,         ((char*)Asl) + 16384 + w * 1024);                      \
    GLOAD_LDS16(Ab + srcA + 32768 + 64, ((char*)Asl) + 16384 + 8192 + w * 1024);               \
    GLOAD_LDS16(Bb + srcA + 64,         ((char*)Bsl) + 32768 + w * 1024);                      \
    GLOAD_LDS16(Bb + srcA + 32768 + 64, ((char*)Bsl) + 32768 + 8192 + w * 1024);               \
    GLOAD_LDS16(Bb + srcA + 65536 + 64, ((char*)Bsl) + 32768 + 16384 + w * 1024);              \
    GLOAD_LDS16(Bb + srcA + 98304 + 64, ((char*)Bsl) + 32768 + 24576 + w * 1024);              \
  }                                                                                            \
  int cur = 0;                                                                                 \
  for (int k = 0; k < 8; ++k) {                                                                \
    __builtin_amdgcn_sched_barrier(0);                                                         \
    if (k < 7) { asm volatile("s_waitcnt vmcnt(6)" ::: "memory"); }                            \
    else       { asm volatile("s_waitcnt vmcnt(0)" ::: "memory"); }                            \
    __builtin_amdgcn_s_barrier();                                                              \
    const s16x8* Acur = Asl + cur * 1024;                                                      \
    const s16x8* Bcur = Bsl + cur * 2048;                                                      \
    int pt = cur + 2; if (pt >= 3) pt -= 3;                                                    \
    const u16* Apf = Ab + srcA + (size_t)(k + 2) * 64;                                         \
    const u16* Bpf = Bb + srcA + (size_t)(k + 2) * 64;                                         \
    char* Adst = ((char*)Asl) + pt * 16384 + w * 1024;                                         \
    char* Bdst = ((char*)Bsl) + pt * 32768 + w * 1024;                                         \
    bool pf = (k < 6);                                                                         \
    /* phase A */                                                                              \
    s16x8 af[4][2], bf0[2][2];                                                                 \
    _Pragma("unroll")                                                                          \
    for (int mi = 0; mi < 4; ++mi) {                                                           \
      int r = wr * 64 + mi * 16 + lo;                                                          \
      _Pragma("unroll")                                                                        \
      for (int kk = 0; kk < 2; ++kk) {                                                         \
        int lc = kk * 4 + hi;                                                                  \
        af[mi][kk] = Acur[r * 8 + (lc ^ (r & 7))];                                             \
      }                                                                                        \
    }                                                                                          \
    _Pragma("unroll")                                                                          \
    for (int ni = 0; ni < 2; ++ni) {                                                           \
      int r = wc * 64 + ni * 16 + lo;                                                          \
      _Pragma("unroll")                                                                        \
      for (int kk = 0; kk < 2; ++kk) {                                                         \
        int lc = kk * 4 + hi;                                                                  \
        bf0[ni][kk] = Bcur[r * 8 + (lc ^ (r & 7))];                                            \
      }                                                                                        \
    }                                                                                          \
    if (pf) {                                                                                  \
      GLOAD_LDS16(Apf, Adst);                                                                  \
      GLOAD_LDS16(Apf + 32768, Adst + 8192);                                                   \
      GLOAD_LDS16(Bpf, Bdst);                                                                  \
    }                                                                                          \
    asm volatile("s_waitcnt lgkmcnt(0)" ::: "memory");                                         \
    __builtin_amdgcn_sched_barrier(0);                                                         \
    __builtin_amdgcn_s_setprio(1);                                                             \
    _Pragma("unroll")                                                                          \
    for (int mi = 0; mi < 4; ++mi)                                                             \
      _Pragma("unroll")                                                                        \
      for (int ni = 0; ni < 2; ++ni)                                                           \
        _Pragma("unroll")                                                                      \
        for (int kk = 0; kk < 2; ++kk)                                                         \
          acc[mi][ni] = MFMA_BF16(af[mi][kk], bf0[ni][kk], acc[mi][ni]);                       \
    __builtin_amdgcn_s_setprio(0);                                                             \
    /* phase B */                                                                              \
    s16x8 bf1[2][2];                                                                           \
    _Pragma("unroll")                                                                          \
    for (int ni = 0; ni < 2; ++ni) {                                                           \
      int r = wc * 64 + (ni + 2) * 16 + lo;                                                    \
      _Pragma("unroll")                                                                        \
      for (int kk = 0; kk < 2; ++kk) {                                                         \
        int lc = kk * 4 + hi;                                                                  \
        bf1[ni][kk] = Bcur[r * 8 + (lc ^ (r & 7))];                                            \
      }                                                                                        \
    }                                                                                          \
    if (pf) {                                                                                  \
      GLOAD_LDS16(Bpf + 32768, Bdst + 8192);                                                   \
      GLOAD_LDS16(Bpf + 65536, Bdst + 16384);                                                  \
      GLOAD_LDS16(Bpf + 98304, Bdst + 24576);                                                  \
    }                                                                                          \
    asm volatile("s_waitcnt lgkmcnt(0)" ::: "memory");                                         \
    __builtin_amdgcn_sched_barrier(0);                                                         \
    __builtin_amdgcn_s_setprio(1);                                                             \
    _Pragma("unroll")                                                                          \
    for (int mi = 0; mi < 4; ++mi)                                                             \
      _Pragma("unroll")                                                                        \
      for (int ni = 0; ni < 2; ++ni)                                                           \
        _Pragma("unroll")                                                                      \
        for (int kk = 0; kk < 2; ++kk)                                                         \
          acc[mi][ni + 2] = MFMA_BF16(af[mi][kk], bf1[ni][kk], acc[mi][ni + 2]);               \
    __builtin_amdgcn_s_setprio(0);                                                             \
    cur = cur + 1; if (cur == 3) cur = 0;                                                      \
  }

// ---------------- K3: qkv GEMM (pipelined) with fused q-softmax epilogue ----------------
// A = w_qkv bf16 [1536][512]; BT = xT [b][4096][512]
// blockIdx.y 0..3 (q): softmax over d, *SCALE -> qT [bh][t][64]
// blockIdx.y 4..11 (k,v): write qkv_b [b][1536][4096]
__launch_bounds__(512, 1)
__global__ void k_gemm_qkv(const u16* __restrict__ A, const u16* __restrict__ BT,
                           u16* __restrict__ C, u16* __restrict__ qT) {
  extern __shared__ char lds[];
  int b = blockIdx.z;
  int m0 = blockIdx.y * 128, n0 = blockIdx.x * 256;
  const u16* Ab = A + (size_t)m0 * 512;
  const u16* Bb = BT + ((size_t)b * 4096 + n0) * 512;
  GEMM_CORE_512(Ab, Bb)
  if (blockIdx.y < 4) {
    int head = (int)blockIdx.y * 2 + wr;
    int bh = b * 8 + head;
#pragma unroll
    for (int ni = 0; ni < 4; ++ni) {
      float mx = -1e30f;
#pragma unroll
      for (int mi = 0; mi < 4; ++mi)
#pragma unroll
        for (int j = 0; j < 4; ++j) mx = fmaxf(mx, acc[mi][ni][j]);
      mx = fmaxf(mx, __shfl_xor(mx, 16));
      mx = fmaxf(mx, __shfl_xor(mx, 32));
      float e[4][4];
      float s = 0.f;
#pragma unroll
      for (int mi = 0; mi < 4; ++mi)
#pragma unroll
        for (int j = 0; j < 4; ++j) { e[mi][j] = __expf(acc[mi][ni][j] - mx); s += e[mi][j]; }
      s += __shfl_xor(s, 16);
      s += __shfl_xor(s, 32);
      float sc = 0.125f / s;  // SCALE = 64^-0.5
      int t = n0 + wc * 64 + ni * 16 + lo;
      u16* op = qT + ((size_t)bh * 4096 + t) * 64 + hi * 4;
#pragma unroll
      for (int mi = 0; mi < 4; ++mi) {
        union { u16 u[4]; uint2 v; } pk;
#pragma unroll
        for (int j = 0; j < 4; ++j) pk.u[j] = f2bf(e[mi][j] * sc);
        *(uint2*)(op + mi * 16) = pk.v;
      }
    }
  } else {
    u16* Cb = C + ((size_t)b * 1536 + m0) * 4096 + n0;
#pragma unroll
    for (int mi = 0; mi < 4; ++mi)
#pragma unroll
      for (int ni = 0; ni < 4; ++ni)
#pragma unroll
        for (int j = 0; j < 4; ++j) {
          int mm = wr * 64 + mi * 16 + hi * 4 + j;
          int nn = wc * 64 + ni * 16 + lo;
          Cb[(size_t)mm * 4096 + nn] = f2bf(acc[mi][ni][j]);
        }
  }
}

// ---------------- K8: w_out GEMM (pipelined) + bias -> ybf bf16, fused GN partials ----------
__launch_bounds__(512, 1)
__global__ void k_gemm_wout(const u16* __restrict__ A, const u16* __restrict__ BT,
                            u16* __restrict__ Ybf, const float* __restrict__ bias,
                            float2* __restrict__ part2) {
  extern __shared__ char lds[];
  int b = blockIdx.z;
  int m0 = blockIdx.y * 128, n0 = blockIdx.x * 256;
  const u16* Ab = A + (size_t)m0 * 512;
  const u16* Bb = BT + ((size_t)b * 4096 + n0) * 512;
  GEMM_CORE_512(Ab, Bb)
  u16* Yb = Ybf + ((size_t)b * 512 + m0) * 4096 + n0;
  float sm = 0.f, ssm = 0.f;
#pragma unroll
  for (int mi = 0; mi < 4; ++mi)
#pragma unroll
    for (int j = 0; j < 4; ++j) {
      int mm = wr * 64 + mi * 16 + hi * 4 + j;
      float bo = bias[m0 + mm];
#pragma unroll
      for (int ni = 0; ni < 4; ++ni) {
        int nn = wc * 64 + ni * 16 + lo;
        float vv = acc[mi][ni][j] + bo;
        sm += vv;
        ssm += vv * vv;
        Yb[(size_t)mm * 4096 + nn] = f2bf(vv);
      }
    }
#pragma unroll
  for (int off = 32; off; off >>= 1) { sm += __shfl_xor(sm, off); ssm += __shfl_xor(ssm, off); }
  // reuse LDS buf0 region (not read during last K-tile, which uses buf 7%3==1)
  float* sr = (float*)lds;
  float* ssr = sr + 8;
  if (lane == 0) { sr[w] = sm; ssr[w] = ssm; }
  __syncthreads();
  if (tid == 0) {
    float2 o;
    o.x = 0.f; o.y = 0.f;
#pragma unroll
    for (int i = 0; i < 8; ++i) { o.x += sr[i]; o.y += ssr[i]; }
    part2[((size_t)b * 4 + blockIdx.y) * 16 + blockIdx.x] = o;
  }
}

// ---------------- K5: k softmax over t (4096), in place on qkv's k region ----------------
__global__ void k_softmax_k(u16* __restrict__ kp) {
  int row = blockIdx.x;  // (b, h*64+d): 4096 rows
  int b = row >> 9, rem = row & 511;
  u16* p = kp + ((size_t)b * 1536 + 512 + rem) * 4096;
  int tid = threadIdx.x, lane = tid & 63, w = tid >> 6;
  s16x8 c0 = ((const s16x8*)p)[tid];
  s16x8 c1 = ((const s16x8*)p)[tid + 256];
  float v[16];
#pragma unroll
  for (int j = 0; j < 8; ++j) { v[j] = bf2f((u16)c0[j]); v[8 + j] = bf2f((u16)c1[j]); }
  float mx = -1e30f;
#pragma unroll
  for (int j = 0; j < 16; ++j) mx = fmaxf(mx, v[j]);
#pragma unroll
  for (int off = 32; off; off >>= 1) mx = fmaxf(mx, __shfl_xor(mx, off));
  __shared__ float redm[4], reds[4];
  if (lane == 0) redm[w] = mx;
  __syncthreads();
  mx = fmaxf(fmaxf(redm[0], redm[1]), fmaxf(redm[2], redm[3]));
  float s = 0.f;
#pragma unroll
  for (int j = 0; j < 16; ++j) { v[j] = __expf(v[j] - mx); s += v[j]; }
#pragma unroll
  for (int off = 32; off; off >>= 1) s += __shfl_xor(s, off);
  if (lane == 0) reds[w] = s;
  __syncthreads();
  s = reds[0] + reds[1] + reds[2] + reds[3];
  float inv = 1.f / s;
  s16x8 o0, o1;
#pragma unroll
  for (int j = 0; j < 8; ++j) { o0[j] = (short)f2bf(v[j] * inv); o1[j] = (short)f2bf(v[8 + j] * inv); }
  ((s16x8*)p)[tid] = o0;
  ((s16x8*)p)[tid + 256] = o1;
}

// ---------------- K6a: context partials over 16 n-slices ----------------
__global__ void k_context_part(const u16* __restrict__ qkv, float* __restrict__ part) {
  int s = blockIdx.x;   // 16 slices of 256 time steps
  int bh = blockIdx.y;  // 64
  int b = bh >> 3, h = bh & 7;
  const u16* vbase = qkv + ((size_t)b * 1536 + 1024 + h * 64) * 4096 + s * 256;
  const u16* kbase = qkv + ((size_t)b * 1536 + 512 + h * 64) * 4096 + s * 256;
  int w = threadIdx.x >> 6, lane = threadIdx.x & 63;
  int e0 = w * 16;
  f32x4 acc[4] = {};
  int er = e0 + (lane & 15);
  int nl = (lane >> 4) * 8;
#pragma unroll
  for (int n0 = 0; n0 < 256; n0 += 32) {
    s16x8 a = *(const s16x8*)(vbase + (size_t)er * 4096 + n0 + nl);
#pragma unroll
    for (int ni = 0; ni < 4; ++ni) {
      s16x8 bb = *(const s16x8*)(kbase + (size_t)(ni * 16 + (lane & 15)) * 4096 + n0 + nl);
      acc[ni] = MFMA_BF16(a, bb, acc[ni]);
    }
  }
  float* cp = part + ((size_t)bh * 16 + s) * 4096;
#pragma unroll
  for (int ni = 0; ni < 4; ++ni)
#pragma unroll
    for (int j = 0; j < 4; ++j) {
      int e = e0 + (lane >> 4) * 4 + j;
      int d = ni * 16 + (lane & 15);
      cp[e * 64 + d] = acc[ni][j];
    }
}

// ---------------- K6b: reduce partials -> ctxT bf16 ----------------
__global__ void k_context_reduce(const float* __restrict__ part, u16* __restrict__ ctxT) {
  int idx = blockIdx.x * 256 + threadIdx.x;  // 262144 total
  int bh = idx >> 12, ed = idx & 4095;
  const float* pp = part + (size_t)bh * 16 * 4096 + ed;
  float sum = 0.f;
#pragma unroll
  for (int s = 0; s < 16; ++s) sum += pp[(size_t)s * 4096];
  ctxT[(size_t)bh * 4096 + ed] = f2bf(sum);
}

// ---------------- K7: attn apply  outT[b][t][h*64+e] = sum_d qT[t][d]*ctxT[e][d] ----------
__launch_bounds__(256, 2)
__global__ void k_attn_out(const u16* __restrict__ qT, const u16* __restrict__ ctxT,
                           u16* __restrict__ outT) {
  __shared__ s16x8 Qs[1024];  // [128 t][8 chunks] swizzled
  __shared__ s16x8 Cs[512];   // [64 e][8 chunks] swizzled
  int bh = blockIdx.y;
  int t0 = blockIdx.x * 128;
  int b = bh >> 3, h = bh & 7;
  const u16* qb = qT + ((size_t)bh * 4096 + t0) * 64;
  const u16* cb = ctxT + (size_t)bh * 64 * 64;
  int tid = threadIdx.x, w = tid >> 6, lane = tid & 63;
#pragma unroll
  for (int it = 0; it < 4; ++it) {
    int L = (w * 4 + it) * 64 + lane;
    int r = L >> 3, lc = (L & 7) ^ (r & 7);
    GLOAD_LDS16(qb + (size_t)r * 64 + lc * 8, ((char*)Qs) + (w * 4 + it) * 1024);
  }
#pragma unroll
  for (int it = 0; it < 2; ++it) {
    int L = (w * 2 + it) * 64 + lane;
    int r = L >> 3, lc = (L & 7) ^ (r & 7);
    GLOAD_LDS16(cb + (size_t)r * 64 + lc * 8, ((char*)Cs) + (w * 2 + it) * 1024);
  }
  asm volatile("s_waitcnt vmcnt(0)");
  __syncthreads();
  f32x4 acc[2][4] = {};
#pragma unroll
  for (int kk = 0; kk < 2; ++kk) {
    int cbi = kk * 4 + (lane >> 4);
    s16x8 af[2], bfr[4];
#pragma unroll
    for (int mi = 0; mi < 2; ++mi) {
      int r = w * 32 + mi * 16 + (lane & 15);
      af[mi] = Qs[r * 8 + (cbi ^ (r & 7))];
    }
#pragma unroll
    for (int ni = 0; ni < 4; ++ni) {
      int r = ni * 16 + (lane & 15);
      bfr[ni] = Cs[r * 8 + (cbi ^ (r & 7))];
    }
#pragma unroll
    for (int mi = 0; mi < 2; ++mi)
#pragma unroll
      for (int ni = 0; ni < 4; ++ni)
        acc[mi][ni] = MFMA_BF16(af[mi], bfr[ni], acc[mi][ni]);
  }
  u16* op = outT + ((size_t)b * 4096 + t0) * 512 + h * 64;
#pragma unroll
  for (int mi = 0; mi < 2; ++mi)
#pragma unroll
    for (int ni = 0; ni < 4; ++ni)
#pragma unroll
      for (int j = 0; j < 4; ++j) {
        int t = w * 32 + mi * 16 + (lane >> 4) * 4 + j;
        int e = ni * 16 + (lane & 15);
        op[(size_t)t * 512 + e] = f2bf(acc[mi][ni][j]);
      }
}

// ---------------- K10: GroupNorm normalize  ybf bf16 -> d_out f32 ----------------
__global__ void k_gn_norm(const u16* __restrict__ ybf, float* __restrict__ y,
                          const float2* __restrict__ part2,
                          const float* __restrict__ gamma, const float* __restrict__ beta) {
  int b = blockIdx.y;
  float s = 0.f, ss = 0.f;
#pragma unroll 8
  for (int i = 0; i < 64; ++i) { float2 pp = part2[b * 64 + i]; s += pp.x; ss += pp.y; }
  const float N = 512.f * 4096.f;
  float mu = s / N;
  float var = ss / N - mu * mu;
  float rstd = rsqrtf(var + 1e-5f);
  size_t base = ((size_t)b << 21) + (size_t)blockIdx.x * 16384;
  const s16x8* ip = (const s16x8*)(ybf + base);
  float4* opf = (float4*)(y + base);
#pragma unroll
  for (int i = 0; i < 8; ++i) {
    int idx = threadIdx.x + i * 256;
    int loc = (int)(blockIdx.x * 16384) + idx * 8;
    int c = loc >> 12;
    float g = gamma[c] * rstd, bt = beta[c];
    s16x8 v = ip[idx];
    float4 o0, o1;
    o0.x = (bf2f((u16)v[0]) - mu) * g + bt;
    o0.y = (bf2f((u16)v[1]) - mu) * g + bt;
    o0.z = (bf2f((u16)v[2]) - mu) * g + bt;
    o0.w = (bf2f((u16)v[3]) - mu) * g + bt;
    o1.x = (bf2f((u16)v[4]) - mu) * g + bt;
    o1.y = (bf2f((u16)v[5]) - mu) * g + bt;
    o1.z = (bf2f((u16)v[6]) - mu) * g + bt;
    o1.w = (bf2f((u16)v[7]) - mu) * g + bt;
    opf[idx * 2] = o0;
    opf[idx * 2 + 1] = o1;
  }
}

extern "C" void kernel_launch(void* const* d_in, const int* in_sizes, int n_in,
                              void* d_out, int out_size, void* d_ws, size_t ws_size,
                              hipStream_t stream) {
  const float* x     = (const float*)d_in[0];
  // d_in[1] = mask: adds 1e-12 to fp32 logits -> numerically dead; ignored.
  const float* wqkv  = (const float*)d_in[2];
  const float* wout  = (const float*)d_in[3];
  const float* bout  = (const float*)d_in[4];
  const float* gamma = (const float*)d_in[5];
  const float* beta  = (const float*)d_in[6];
  float* y = (float*)d_out;

  char* ws = (char*)d_ws;
  u16*    qkv_b = (u16*)ws;                   // 100,663,296 B [8][1536][4096] bf16 (q region unused)
  u16*    ybf   = (u16*)ws;                   //  overlay: 33,554,432 B [8][512][4096] bf16
  u16*    xT    = (u16*)(ws + 100663296);     //  33,554,432 B [8][4096][512] bf16
  u16*    outT  = xT;                         //  overlay (xT dead after K3)
  u16*    qT    = (u16*)(ws + 134217728);     //  33,554,432 B [64][4096][64] bf16
  u16*    wqkvb = (u16*)(ws + 167772160);     //   1,572,864 B
  u16*    woutb = (u16*)(ws + 169345024);     //     524,288 B
  u16*    ctxT  = (u16*)(ws + 169869312);     //     524,288 B [64][64][64] bf16
  float2* part2 = (float2*)(ws + 170393600);  //       8,192 B
  float*  ctxpp = (float*)(ws + 170401792);   //  16,777,216 B [64][16][64][64] f32

  const int GEMM_LDS = 147456;
  (void)hipFuncSetAttribute((const void*)k_gemm_qkv,
                            hipFuncAttributeMaxDynamicSharedMemorySize, GEMM_LDS);
  (void)hipFuncSetAttribute((const void*)k_gemm_wout,
                            hipFuncAttributeMaxDynamicSharedMemorySize, GEMM_LDS);

  k_convert_w<<<1024, 256, 0, stream>>>(wqkv, wout, wqkvb, woutb);
  {
    dim3 g(64, 8, 8);
    k_transpose_x<<<g, 256, 0, stream>>>(x, xT);
  }
  {
    dim3 g(16, 12, 8);
    k_gemm_qkv<<<g, 512, GEMM_LDS, stream>>>(wqkvb, xT, qkv_b, qT);
  }
  k_softmax_k<<<4096, 256, 0, stream>>>(qkv_b);
  {
    dim3 g(16, 64);
    k_context_part<<<g, 256, 0, stream>>>(qkv_b, ctxpp);
  }
  k_context_reduce<<<1024, 256, 0, stream>>>(ctxpp, ctxT);
  {
    dim3 g(32, 64);
    k_attn_out<<<g, 256, 0, stream>>>(qT, ctxT, outT);
  }
  {
    dim3 g(16, 4, 8);
    k_gemm_wout<<<g, 512, GEMM_LDS, stream>>>(woutb, outT, ybf, bout, part2);
  }
  {
    dim3 g(128, 8);
    k_gn_norm<<<g, 256, 0, stream>>>(ybf, y, part2, gamma, beta);
  }
}

// Round 5
// 177.905 us; speedup vs baseline: 1.4543x; 1.0081x over previous
//
#include <hip/hip_runtime.h>
#include <stdint.h>

typedef unsigned short u16;
using f32x4 = __attribute__((ext_vector_type(4))) float;
using s16x8 = __attribute__((ext_vector_type(8))) short;

#define MFMA_BF16(a, b, c) __builtin_amdgcn_mfma_f32_16x16x32_bf16((a), (b), (c), 0, 0, 0)

#define GLOAD_LDS16(gptr, lptr)                                                               \
  __builtin_amdgcn_global_load_lds((const __attribute__((address_space(1))) uint32_t*)(gptr), \
                                   (__attribute__((address_space(3))) uint32_t*)(lptr), 16, 0, 0)

__device__ __forceinline__ u16 f2bf(float f) {
  union { float f; uint32_t u; } v; v.f = f;
  uint32_t r = v.u + 0x7fffu + ((v.u >> 16) & 1u);
  return (u16)(r >> 16);
}
__device__ __forceinline__ float bf2f(u16 h) {
  union { uint32_t u; float f; } v; v.u = ((uint32_t)h) << 16;
  return v.f;
}

// ---------------- K1: convert weights fp32 -> bf16 ----------------
__global__ void k_convert_w(const float* __restrict__ wq, const float* __restrict__ wo,
                            u16* __restrict__ wqb, u16* __restrict__ wob) {
  int i = blockIdx.x * 256 + threadIdx.x;
  const int nq = 1536 * 512 / 4;
  const int no = 512 * 512 / 4;
  if (i < nq) {
    float4 v = ((const float4*)wq)[i];
    u16* o = wqb + i * 4;
    o[0] = f2bf(v.x); o[1] = f2bf(v.y); o[2] = f2bf(v.z); o[3] = f2bf(v.w);
  } else if (i < nq + no) {
    int j = i - nq;
    float4 v = ((const float4*)wo)[j];
    u16* o = wob + j * 4;
    o[0] = f2bf(v.x); o[1] = f2bf(v.y); o[2] = f2bf(v.z); o[3] = f2bf(v.w);
  }
}

// ---------------- K2: x [b][c][t] f32 -> xT [b][t][c] bf16 ----------------
__global__ void k_transpose_x(const float* __restrict__ x, u16* __restrict__ xT) {
  __shared__ u16 tile[64][65];
  int b = blockIdx.z, c0 = blockIdx.y * 64, t0 = blockIdx.x * 64;
  const float* xp = x + ((size_t)b * 512 + c0) * 4096 + t0;
#pragma unroll
  for (int i = 0; i < 16; ++i) {
    int idx = threadIdx.x + i * 256;
    int r = idx >> 6, col = idx & 63;
    tile[r][col] = f2bf(xp[(size_t)r * 4096 + col]);
  }
  __syncthreads();
  u16* op = xT + ((size_t)b * 4096 + t0) * 512 + c0;
#pragma unroll
  for (int i = 0; i < 16; ++i) {
    int idx = threadIdx.x + i * 256;
    int r = idx >> 6, col = idx & 63;
    op[(size_t)r * 512 + col] = tile[col][r];
  }
}

// ---------------- K3: qkv GEMM (m97 structure) with fused q-softmax epilogue ----------------
// A = w_qkv bf16 [1536][512]; BT = xT [b][4096][512]
// m-tiles 0..3 (q): softmax over d, *SCALE -> qT [bh][t][64]
// m-tiles 4..11 (k,v): write RAW k,v to qkv_b [b][1536][4096]
__launch_bounds__(256, 2)
__global__ void k_gemm_qkv(const u16* __restrict__ A, const u16* __restrict__ BT,
                           u16* __restrict__ C, u16* __restrict__ qT) {
  __shared__ s16x8 As8[1024];  // [128 rows][8 chunks], physical chunk = logical ^ (row&7)
  __shared__ s16x8 Bs8[1024];
  int b = blockIdx.z;
  int m0 = blockIdx.y * 128, n0 = blockIdx.x * 128;
  const u16* Ab = A + (size_t)m0 * 512;
  const u16* Bb = BT + ((size_t)b * 4096 + n0) * 512;
  int tid = threadIdx.x, w = tid >> 6, lane = tid & 63;
  int wm = (w >> 1) * 64, wn = (w & 1) * 64;
  f32x4 acc[4][4] = {};
  for (int kt = 0; kt < 8; ++kt) {
    if (kt) __syncthreads();
#pragma unroll
    for (int it = 0; it < 4; ++it) {
      int L = (w * 4 + it) * 64 + lane;
      int r = L >> 3;
      int lc = (L & 7) ^ (r & 7);
      GLOAD_LDS16(Ab + (size_t)r * 512 + kt * 64 + lc * 8, ((char*)As8) + (w * 4 + it) * 1024);
      GLOAD_LDS16(Bb + (size_t)r * 512 + kt * 64 + lc * 8, ((char*)Bs8) + (w * 4 + it) * 1024);
    }
    asm volatile("s_waitcnt vmcnt(0)");
    __syncthreads();
#pragma unroll
    for (int kk = 0; kk < 2; ++kk) {
      int cb = kk * 4 + (lane >> 4);
      s16x8 af[4], bfr[4];
#pragma unroll
      for (int mi = 0; mi < 4; ++mi) {
        int r = wm + mi * 16 + (lane & 15);
        af[mi] = As8[r * 8 + (cb ^ (r & 7))];
      }
#pragma unroll
      for (int ni = 0; ni < 4; ++ni) {
        int r = wn + ni * 16 + (lane & 15);
        bfr[ni] = Bs8[r * 8 + (cb ^ (r & 7))];
      }
#pragma unroll
      for (int mi = 0; mi < 4; ++mi)
#pragma unroll
        for (int ni = 0; ni < 4; ++ni)
          acc[mi][ni] = MFMA_BF16(af[mi], bfr[ni], acc[mi][ni]);
    }
  }
  if (blockIdx.y < 4) {
    // q region: this warp's 64 m-rows == one full head's d range.
    int head = (m0 >> 6) + (wm >> 6);
    int bh = b * 8 + head;
#pragma unroll
    for (int ni = 0; ni < 4; ++ni) {
      float mx = -1e30f;
#pragma unroll
      for (int mi = 0; mi < 4; ++mi)
#pragma unroll
        for (int j = 0; j < 4; ++j) mx = fmaxf(mx, acc[mi][ni][j]);
      mx = fmaxf(mx, __shfl_xor(mx, 16));
      mx = fmaxf(mx, __shfl_xor(mx, 32));
      float e[4][4];
      float s = 0.f;
#pragma unroll
      for (int mi = 0; mi < 4; ++mi)
#pragma unroll
        for (int j = 0; j < 4; ++j) { e[mi][j] = __expf(acc[mi][ni][j] - mx); s += e[mi][j]; }
      s += __shfl_xor(s, 16);
      s += __shfl_xor(s, 32);
      float sc = 0.125f / s;  // SCALE = 64^-0.5
      int t = n0 + wn + ni * 16 + (lane & 15);
      u16* op = qT + ((size_t)bh * 4096 + t) * 64 + (lane >> 4) * 4;
#pragma unroll
      for (int mi = 0; mi < 4; ++mi) {
        union { u16 u[4]; uint2 v; } pk;
#pragma unroll
        for (int j = 0; j < 4; ++j) pk.u[j] = f2bf(e[mi][j] * sc);
        *(uint2*)(op + mi * 16) = pk.v;
      }
    }
  } else {
    u16* Cb = C + ((size_t)b * 1536 + m0) * 4096 + n0;
#pragma unroll
    for (int mi = 0; mi < 4; ++mi)
#pragma unroll
      for (int ni = 0; ni < 4; ++ni)
#pragma unroll
        for (int j = 0; j < 4; ++j) {
          int mm = wm + mi * 16 + (lane >> 4) * 4 + j;
          int nn = wn + ni * 16 + (lane & 15);
          Cb[(size_t)mm * 4096 + nn] = f2bf(acc[mi][ni][j]);
        }
  }
}

// ---------------- K4: context partials with on-the-fly exp(k) ----------------
// Per block (slice s of 256 n, bh): wave w owns d-rows [w*16, w*16+16).
// ctxp[bh][s][d][e] = sum_{n in slice} exp(k[d][n]) * v[e][n]   (f32, unnormalized)
// spart[bh][s][d]  = sum_{n in slice} exp(k[d][n])
// No max subtraction: |k| <~ 6 (k ~ N(0,1)), exp safe in fp32/bf16.
__global__ void k_context_part(const u16* __restrict__ qkv, float* __restrict__ ctxp,
                               float* __restrict__ spart) {
  int s = blockIdx.x, bh = blockIdx.y;
  int b = bh >> 3, h = bh & 7;
  int w = threadIdx.x >> 6, lane = threadIdx.x & 63;
  int hi = lane >> 4, lo = lane & 15;
  const u16* vb = qkv + ((size_t)b * 1536 + 1024 + h * 64) * 4096 + s * 256;
  const u16* kb = qkv + ((size_t)b * 1536 + 512 + h * 64) * 4096 + s * 256;
  int d = w * 16 + lo;
  f32x4 acc[4] = {};
  float ssum = 0.f;
#pragma unroll
  for (int st = 0; st < 8; ++st) {
    int nn = st * 32 + hi * 8;
    s16x8 braw = *(const s16x8*)(kb + (size_t)d * 4096 + nn);
    s16x8 bexp;
#pragma unroll
    for (int j = 0; j < 8; ++j) {
      float f = __expf(bf2f((u16)braw[j]));
      ssum += f;
      bexp[j] = (short)f2bf(f);
    }
#pragma unroll
    for (int ei = 0; ei < 4; ++ei) {
      s16x8 a = *(const s16x8*)(vb + (size_t)(ei * 16 + lo) * 4096 + nn);
      acc[ei] = MFMA_BF16(a, bexp, acc[ei]);
    }
  }
  // C frag: row (A-dim e) = ei*16 + hi*4 + j ; col (B-dim d) = w*16 + lo
  float* cp = ctxp + ((size_t)bh * 16 + s) * 4096;
#pragma unroll
  for (int ei = 0; ei < 4; ++ei) {
    float4 o;
    o.x = acc[ei][0]; o.y = acc[ei][1]; o.z = acc[ei][2]; o.w = acc[ei][3];
    *(float4*)&cp[(size_t)d * 64 + ei * 16 + hi * 4] = o;
  }
  ssum += __shfl_xor(ssum, 16);
  ssum += __shfl_xor(ssum, 32);
  if (lane < 16) spart[((size_t)bh * 16 + s) * 64 + w * 16 + lane] = ssum;
}

// ---------------- K5: reduce ctx partials + normalize -> Bg [bh][d][e] bf16 ----------------
__global__ void k_ctx_reduce(const float* __restrict__ ctxp, const float* __restrict__ spart,
                             u16* __restrict__ Bg) {
  int q = blockIdx.x, bh = blockIdx.y;  // q: 16 chunks of 256 positions (4 d-rows)
  __shared__ float sinv[4];
  int tid = threadIdx.x;
  if (tid < 4) {
    int d = q * 4 + tid;
    float s = 0.f;
#pragma unroll
    for (int si = 0; si < 16; ++si) s += spart[((size_t)bh * 16 + si) * 64 + d];
    sinv[tid] = 1.f / s;
  }
  __syncthreads();
  int pos = q * 256 + tid;
  float v = 0.f;
#pragma unroll
  for (int si = 0; si < 16; ++si) v += ctxp[((size_t)bh * 16 + si) * 4096 + pos];
  Bg[(size_t)bh * 4096 + pos] = f2bf(v * sinv[(pos >> 6) & 3]);
}

// ---------------- K6: Wfused[b][m][h*64+d] = sum_e wout[m][h*64+e] * Bg[bh][d][e] ----------
// Grid: 64 blocks (b,h), 256 threads (4 waves); wave w: m-rows [w*128, w*128+128).
__global__ void k_wfused(const u16* __restrict__ wout, const u16* __restrict__ Bg,
                         u16* __restrict__ Wf) {
  int bh = blockIdx.x;
  int b = bh >> 3, h = bh & 7;
  int w = threadIdx.x >> 6, lane = threadIdx.x & 63;
  int hi = lane >> 4, lo = lane & 15;
  const u16* Bb = Bg + (size_t)bh * 4096;
  const u16* Ab = wout + (size_t)h * 64;
  f32x4 acc[8][4] = {};
#pragma unroll
  for (int ks = 0; ks < 2; ++ks) {
    s16x8 bfr[4];
#pragma unroll
    for (int ni = 0; ni < 4; ++ni)
      bfr[ni] = *(const s16x8*)(Bb + (size_t)(ni * 16 + lo) * 64 + ks * 32 + hi * 8);
#pragma unroll
    for (int mi = 0; mi < 8; ++mi) {
      s16x8 a = *(const s16x8*)(Ab + (size_t)(w * 128 + mi * 16 + lo) * 512 + ks * 32 + hi * 8);
#pragma unroll
      for (int ni = 0; ni < 4; ++ni) acc[mi][ni] = MFMA_BF16(a, bfr[ni], acc[mi][ni]);
    }
  }
#pragma unroll
  for (int mi = 0; mi < 8; ++mi)
#pragma unroll
    for (int ni = 0; ni < 4; ++ni) {
      int m = w * 128 + mi * 16 + hi * 4;
      int d = ni * 16 + lo;
#pragma unroll
      for (int j = 0; j < 4; ++j)
        Wf[((size_t)b * 512 + m + j) * 512 + h * 64 + d] = f2bf(acc[mi][ni][j]);
    }
}

// ---------------- K7: final GEMM  y[b][m][t] = sum_hd Wf[b][m][hd]*qT[bh][t][d] + bias ------
// + fused GN partial sums; output ybf bf16.
__launch_bounds__(256, 2)
__global__ void k_gemm_final(const u16* __restrict__ Wf, const u16* __restrict__ qT,
                             u16* __restrict__ Ybf, const float* __restrict__ bias,
                             float2* __restrict__ part2) {
  __shared__ s16x8 As8[1024];
  __shared__ s16x8 Bs8[1024];
  int b = blockIdx.z;
  int m0 = blockIdx.y * 128, n0 = blockIdx.x * 128;
  const u16* Ab = Wf + ((size_t)b * 512 + m0) * 512;
  const u16* qTb = qT + (size_t)b * 8 * 4096 * 64;
  int tid = threadIdx.x, w = tid >> 6, lane = tid & 63;
  int wm = (w >> 1) * 64, wn = (w & 1) * 64;
  f32x4 acc[4][4] = {};
  for (int kt = 0; kt < 8; ++kt) {
    if (kt) __syncthreads();
#pragma unroll
    for (int it = 0; it < 4; ++it) {
      int L = (w * 4 + it) * 64 + lane;
      int r = L >> 3;
      int lc = (L & 7) ^ (r & 7);
      GLOAD_LDS16(Ab + (size_t)r * 512 + kt * 64 + lc * 8, ((char*)As8) + (w * 4 + it) * 1024);
      int G = kt * 8 + lc;  // global K-chunk: head = G>>3, d-chunk = G&7
      GLOAD_LDS16(qTb + ((size_t)(G >> 3) * 4096 + n0 + r) * 64 + (G & 7) * 8,
                  ((char*)Bs8) + (w * 4 + it) * 1024);
    }
    asm volatile("s_waitcnt vmcnt(0)");
    __syncthreads();
#pragma unroll
    for (int kk = 0; kk < 2; ++kk) {
      int cb = kk * 4 + (lane >> 4);
      s16x8 af[4], bfr[4];
#pragma unroll
      for (int mi = 0; mi < 4; ++mi) {
        int r = wm + mi * 16 + (lane & 15);
        af[mi] = As8[r * 8 + (cb ^ (r & 7))];
      }
#pragma unroll
      for (int ni = 0; ni < 4; ++ni) {
        int r = wn + ni * 16 + (lane & 15);
        bfr[ni] = Bs8[r * 8 + (cb ^ (r & 7))];
      }
#pragma unroll
      for (int mi = 0; mi < 4; ++mi)
#pragma unroll
        for (int ni = 0; ni < 4; ++ni)
          acc[mi][ni] = MFMA_BF16(af[mi], bfr[ni], acc[mi][ni]);
    }
  }
  u16* Yb = Ybf + ((size_t)b * 512 + m0) * 4096 + n0;
  float sm = 0.f, ssm = 0.f;
#pragma unroll
  for (int mi = 0; mi < 4; ++mi)
#pragma unroll
    for (int j = 0; j < 4; ++j) {
      int mm = wm + mi * 16 + (lane >> 4) * 4 + j;
      float bo = bias[m0 + mm];
#pragma unroll
      for (int ni = 0; ni < 4; ++ni) {
        int nn = wn + ni * 16 + (lane & 15);
        float vv = acc[mi][ni][j] + bo;
        sm += vv;
        ssm += vv * vv;
        Yb[(size_t)mm * 4096 + nn] = f2bf(vv);
      }
    }
#pragma unroll
  for (int off = 32; off; off >>= 1) { sm += __shfl_xor(sm, off); ssm += __shfl_xor(ssm, off); }
  __shared__ float sr[4], ssr[4];
  if (lane == 0) { sr[w] = sm; ssr[w] = ssm; }
  __syncthreads();
  if (tid == 0) {
    float2 o;
    o.x = sr[0] + sr[1] + sr[2] + sr[3];
    o.y = ssr[0] + ssr[1] + ssr[2] + ssr[3];
    part2[((size_t)b * 4 + blockIdx.y) * 32 + blockIdx.x] = o;
  }
}

// ---------------- K8: GroupNorm normalize  ybf bf16 -> d_out f32 ----------------
__global__ void k_gn_norm(const u16* __restrict__ ybf, float* __restrict__ y,
                          const float2* __restrict__ part2,
                          const float* __restrict__ gamma, const float* __restrict__ beta) {
  int b = blockIdx.y;
  float s = 0.f, ss = 0.f;
#pragma unroll 8
  for (int i = 0; i < 128; ++i) { float2 pp = part2[b * 128 + i]; s += pp.x; ss += pp.y; }
  const float N = 512.f * 4096.f;
  float mu = s / N;
  float var = ss / N - mu * mu;
  float rstd = rsqrtf(var + 1e-5f);
  size_t base = ((size_t)b << 21) + (size_t)blockIdx.x * 16384;
  const s16x8* ip = (const s16x8*)(ybf + base);
  float4* opf = (float4*)(y + base);
#pragma unroll
  for (int i = 0; i < 8; ++i) {
    int idx = threadIdx.x + i * 256;
    int loc = (int)(blockIdx.x * 16384) + idx * 8;
    int c = loc >> 12;
    float g = gamma[c] * rstd, bt = beta[c];
    s16x8 v = ip[idx];
    float4 o0, o1;
    o0.x = (bf2f((u16)v[0]) - mu) * g + bt;
    o0.y = (bf2f((u16)v[1]) - mu) * g + bt;
    o0.z = (bf2f((u16)v[2]) - mu) * g + bt;
    o0.w = (bf2f((u16)v[3]) - mu) * g + bt;
    o1.x = (bf2f((u16)v[4]) - mu) * g + bt;
    o1.y = (bf2f((u16)v[5]) - mu) * g + bt;
    o1.z = (bf2f((u16)v[6]) - mu) * g + bt;
    o1.w = (bf2f((u16)v[7]) - mu) * g + bt;
    opf[idx * 2] = o0;
    opf[idx * 2 + 1] = o1;
  }
}

extern "C" void kernel_launch(void* const* d_in, const int* in_sizes, int n_in,
                              void* d_out, int out_size, void* d_ws, size_t ws_size,
                              hipStream_t stream) {
  const float* x     = (const float*)d_in[0];
  // d_in[1] = mask: adds 1e-12 to fp32 logits -> numerically dead; ignored.
  const float* wqkv  = (const float*)d_in[2];
  const float* wout  = (const float*)d_in[3];
  const float* bout  = (const float*)d_in[4];
  const float* gamma = (const float*)d_in[5];
  const float* beta  = (const float*)d_in[6];
  float* y = (float*)d_out;

  char* ws = (char*)d_ws;
  u16*    qkv_b = (u16*)ws;                   // 100,663,296 B [8][1536][4096] bf16 (k,v raw; q unused)
  u16*    ybf   = (u16*)ws;                   //  overlay: 33,554,432 B [8][512][4096] bf16
  u16*    xT    = (u16*)(ws + 100663296);     //  33,554,432 B [8][4096][512] bf16 (dead after K3)
  float*  ctxp  = (float*)(ws + 100663296);   //  overlay: 16,777,216 B [64][16][4096] f32
  float*  spart = (float*)(ws + 117440512);   //     262,144 B [64][16][64] f32
  u16*    Bg    = (u16*)(ws + 117702656);     //     524,288 B [64][4096] bf16 (normalized ctx^T)
  u16*    qT    = (u16*)(ws + 134217728);     //  33,554,432 B [64][4096][64] bf16
  u16*    wqkvb = (u16*)(ws + 167772160);     //   1,572,864 B
  u16*    woutb = (u16*)(ws + 169345024);     //     524,288 B
  u16*    Wfused= (u16*)(ws + 169869312);     //   4,194,304 B [8][512][512] bf16
  float2* part2 = (float2*)(ws + 174063616);  //       8,192 B

  k_convert_w<<<1024, 256, 0, stream>>>(wqkv, wout, wqkvb, woutb);
  {
    dim3 g(64, 8, 8);
    k_transpose_x<<<g, 256, 0, stream>>>(x, xT);
  }
  {
    dim3 g(32, 12, 8);
    k_gemm_qkv<<<g, 256, 0, stream>>>(wqkvb, xT, qkv_b, qT);
  }
  {
    dim3 g(16, 64);
    k_context_part<<<g, 256, 0, stream>>>(qkv_b, ctxp, spart);
  }
  {
    dim3 g(16, 64);
    k_ctx_reduce<<<g, 256, 0, stream>>>(ctxp, spart, Bg);
  }
  k_wfused<<<64, 256, 0, stream>>>(woutb, Bg, Wfused);
  {
    dim3 g(32, 4, 8);
    k_gemm_final<<<g, 256, 0, stream>>>(Wfused, qT, ybf, bout, part2);
  }
  {
    dim3 g(128, 8);
    k_gn_norm<<<g, 256, 0, stream>>>(ybf, y, part2, gamma, beta);
  }
}

// Round 6
// 176.305 us; speedup vs baseline: 1.4675x; 1.0091x over previous
//
#include <hip/hip_runtime.h>
#include <stdint.h>

typedef unsigned short u16;
using f32x4 = __attribute__((ext_vector_type(4))) float;
using s16x8 = __attribute__((ext_vector_type(8))) short;

#define MFMA_BF16(a, b, c) __builtin_amdgcn_mfma_f32_16x16x32_bf16((a), (b), (c), 0, 0, 0)

#define GLOAD_LDS16(gptr, lptr)                                                               \
  __builtin_amdgcn_global_load_lds((const __attribute__((address_space(1))) uint32_t*)(gptr), \
                                   (__attribute__((address_space(3))) uint32_t*)(lptr), 16, 0, 0)

__device__ __forceinline__ u16 f2bf(float f) {
  union { float f; uint32_t u; } v; v.f = f;
  uint32_t r = v.u + 0x7fffu + ((v.u >> 16) & 1u);
  return (u16)(r >> 16);
}
__device__ __forceinline__ float bf2f(u16 h) {
  union { uint32_t u; float f; } v; v.u = ((uint32_t)h) << 16;
  return v.f;
}

// ---------------- K1: convert weights fp32 -> bf16 ----------------
__global__ void k_convert_w(const float* __restrict__ wq, const float* __restrict__ wo,
                            u16* __restrict__ wqb, u16* __restrict__ wob) {
  int i = blockIdx.x * 256 + threadIdx.x;
  const int nq = 1536 * 512 / 4;
  const int no = 512 * 512 / 4;
  if (i < nq) {
    float4 v = ((const float4*)wq)[i];
    u16* o = wqb + i * 4;
    o[0] = f2bf(v.x); o[1] = f2bf(v.y); o[2] = f2bf(v.z); o[3] = f2bf(v.w);
  } else if (i < nq + no) {
    int j = i - nq;
    float4 v = ((const float4*)wo)[j];
    u16* o = wob + j * 4;
    o[0] = f2bf(v.x); o[1] = f2bf(v.y); o[2] = f2bf(v.z); o[3] = f2bf(v.w);
  }
}

// ---------------- K2: x [b][c][t] f32 -> xT [b][t][c] bf16 ----------------
__global__ void k_transpose_x(const float* __restrict__ x, u16* __restrict__ xT) {
  __shared__ u16 tile[64][65];
  int b = blockIdx.z, c0 = blockIdx.y * 64, t0 = blockIdx.x * 64;
  const float* xp = x + ((size_t)b * 512 + c0) * 4096 + t0;
#pragma unroll
  for (int i = 0; i < 16; ++i) {
    int idx = threadIdx.x + i * 256;
    int r = idx >> 6, col = idx & 63;
    tile[r][col] = f2bf(xp[(size_t)r * 4096 + col]);
  }
  __syncthreads();
  u16* op = xT + ((size_t)b * 4096 + t0) * 512 + c0;
#pragma unroll
  for (int i = 0; i < 16; ++i) {
    int idx = threadIdx.x + i * 256;
    int r = idx >> 6, col = idx & 63;
    op[(size_t)r * 512 + col] = tile[col][r];
  }
}

// ===== 8-wave pipelined GEMM core: BM=128, BN=256, BK=64, 512 thr, ring-3 LDS (144KB) =====
// LDS rows x 8 chunks of 16B; physical chunk = logical ^ (row&7) (proven 0-conflict).
// Per K-tile kt: vmcnt(6); s_barrier; phaseA{8 ds_read kk0 | stage A0,A1,B0 of kt+2 |
// setprio(1) 16 MFMA} ; s_barrier ; phaseB{8 ds_read kk1 | stage B1,B2,B3 | 16 MFMA}.
// No lgkmcnt/sched_barrier fences: compiler schedules intra-phase (m141 lesson).
// FIFO: each tile = 6 loads/thread; vmcnt(6) leaves exactly tile kt+1 in flight.
// WAR: buf (kt+2)%3 holds tile kt-1, fully read before this tile's top barrier.
#define GEMM8W_CORE(ABASE, BSRC)                                                      \
  s16x8* Asl = (s16x8*)lds;            /* 3 * 1024 granules = 48KB */                 \
  s16x8* Bsl = (s16x8*)(lds + 49152);  /* 3 * 2048 granules = 96KB */                 \
  int tid = threadIdx.x, w = tid >> 6, lane = tid & 63;                               \
  int wr = w >> 2, wc = w & 3;                                                        \
  int hi = lane >> 4, lo = lane & 15;                                                 \
  int rsu = tid >> 3, pc = tid & 7;                                                   \
  int lcs = pc ^ (rsu & 7);                                                           \
  f32x4 acc[4][4] = {};                                                               \
  _Pragma("unroll")                                                                   \
  for (int t = 0; t < 2; ++t) {                                                       \
    _Pragma("unroll")                                                                 \
    for (int u = 0; u < 2; ++u) {                                                     \
      int rr = u * 64 + rsu;                                                          \
      GLOAD_LDS16(ABASE + (size_t)rr * 512 + t * 64 + lcs * 8,                        \
                  ((char*)Asl) + ((size_t)t * 1024 + rr * 8 + pc) * 16);              \
    }                                                                                 \
    _Pragma("unroll")                                                                 \
    for (int u = 0; u < 4; ++u) {                                                     \
      int rr = u * 64 + rsu;                                                          \
      GLOAD_LDS16(BSRC(rr, t, lcs),                                                   \
                  ((char*)Bsl) + ((size_t)t * 2048 + rr * 8 + pc) * 16);              \
    }                                                                                 \
  }                                                                                   \
  for (int kt = 0; kt < 8; ++kt) {                                                    \
    if (kt < 7) { asm volatile("s_waitcnt vmcnt(6)" ::: "memory"); }                  \
    else        { asm volatile("s_waitcnt vmcnt(0)" ::: "memory"); }                  \
    __builtin_amdgcn_s_barrier();                                                     \
    int bufc = kt % 3, bufs = (kt + 2) % 3;                                           \
    const s16x8* Ac = Asl + bufc * 1024;                                              \
    const s16x8* Bc = Bsl + bufc * 2048;                                              \
    bool st = (kt < 6);                                                               \
    s16x8 af[4], bfr[4];                                                              \
    _Pragma("unroll")                                                                 \
    for (int mi = 0; mi < 4; ++mi) {                                                  \
      int r = wr * 64 + mi * 16 + lo;                                                 \
      af[mi] = Ac[r * 8 + (hi ^ (r & 7))];                                            \
    }                                                                                 \
    _Pragma("unroll")                                                                 \
    for (int ni = 0; ni < 4; ++ni) {                                                  \
      int r = wc * 64 + ni * 16 + lo;                                                 \
      bfr[ni] = Bc[r * 8 + (hi ^ (r & 7))];                                           \
    }                                                                                 \
    if (st) {                                                                         \
      _Pragma("unroll")                                                               \
      for (int u = 0; u < 2; ++u) {                                                   \
        int rr = u * 64 + rsu;                                                        \
        GLOAD_LDS16(ABASE + (size_t)rr * 512 + (kt + 2) * 64 + lcs * 8,               \
                    ((char*)Asl) + ((size_t)bufs * 1024 + rr * 8 + pc) * 16);         \
      }                                                                               \
      {                                                                               \
        int rr = rsu;                                                                 \
        GLOAD_LDS16(BSRC(rr, (kt + 2), lcs),                                          \
                    ((char*)Bsl) + ((size_t)bufs * 2048 + rr * 8 + pc) * 16);         \
      }                                                                               \
    }                                                                                 \
    __builtin_amdgcn_s_setprio(1);                                                    \
    _Pragma("unroll")                                                                 \
    for (int mi = 0; mi < 4; ++mi)                                                    \
      _Pragma("unroll")                                                               \
      for (int ni = 0; ni < 4; ++ni)                                                  \
        acc[mi][ni] = MFMA_BF16(af[mi], bfr[ni], acc[mi][ni]);                        \
    __builtin_amdgcn_s_setprio(0);                                                    \
    __builtin_amdgcn_s_barrier();                                                     \
    _Pragma("unroll")                                                                 \
    for (int mi = 0; mi < 4; ++mi) {                                                  \
      int r = wr * 64 + mi * 16 + lo;                                                 \
      af[mi] = Ac[r * 8 + ((4 + hi) ^ (r & 7))];                                      \
    }                                                                                 \
    _Pragma("unroll")                                                                 \
    for (int ni = 0; ni < 4; ++ni) {                                                  \
      int r = wc * 64 + ni * 16 + lo;                                                 \
      bfr[ni] = Bc[r * 8 + ((4 + hi) ^ (r & 7))];                                     \
    }                                                                                 \
    if (st) {                                                                         \
      _Pragma("unroll")                                                               \
      for (int u = 1; u < 4; ++u) {                                                   \
        int rr = u * 64 + rsu;                                                        \
        GLOAD_LDS16(BSRC(rr, (kt + 2), lcs),                                          \
                    ((char*)Bsl) + ((size_t)bufs * 2048 + rr * 8 + pc) * 16);         \
      }                                                                               \
    }                                                                                 \
    __builtin_amdgcn_s_setprio(1);                                                    \
    _Pragma("unroll")                                                                 \
    for (int mi = 0; mi < 4; ++mi)                                                    \
      _Pragma("unroll")                                                               \
      for (int ni = 0; ni < 4; ++ni)                                                  \
        acc[mi][ni] = MFMA_BF16(af[mi], bfr[ni], acc[mi][ni]);                        \
    __builtin_amdgcn_s_setprio(0);                                                    \
  }

#define BSRC_X(rr, ktile, lc) (Bb + (size_t)(rr) * 512 + (ktile) * 64 + (lc) * 8)
#define BSRC_Q(rr, ktile, lc) (Bq + (size_t)(ktile) * 262144 + (size_t)(rr) * 64 + (lc) * 8)

// ---------------- K3: qkv GEMM (pipelined 8-wave) with fused q-softmax epilogue ----------
// A = w_qkv bf16 [1536][512]; BT = xT [b][4096][512]
// blockIdx.y 0..3 (q): softmax over d, *SCALE -> qT [bh][t][64]; head = y*2 + wr
// blockIdx.y 4..11 (k,v): write raw to qkv_b [b][1536][4096]
__launch_bounds__(512, 1)
__global__ void k_gemm_qkv(const u16* __restrict__ A, const u16* __restrict__ BT,
                           u16* __restrict__ C, u16* __restrict__ qT) {
  extern __shared__ char lds[];
  int b = blockIdx.z;
  int m0 = blockIdx.y * 128, n0 = blockIdx.x * 256;
  const u16* Ab = A + (size_t)m0 * 512;
  const u16* Bb = BT + ((size_t)b * 4096 + n0) * 512;
  GEMM8W_CORE(Ab, BSRC_X)
  if (blockIdx.y < 4) {
    int head = (int)blockIdx.y * 2 + wr;
    int bh = b * 8 + head;
#pragma unroll
    for (int ni = 0; ni < 4; ++ni) {
      float mx = -1e30f;
#pragma unroll
      for (int mi = 0; mi < 4; ++mi)
#pragma unroll
        for (int j = 0; j < 4; ++j) mx = fmaxf(mx, acc[mi][ni][j]);
      mx = fmaxf(mx, __shfl_xor(mx, 16));
      mx = fmaxf(mx, __shfl_xor(mx, 32));
      float e[4][4];
      float s = 0.f;
#pragma unroll
      for (int mi = 0; mi < 4; ++mi)
#pragma unroll
        for (int j = 0; j < 4; ++j) { e[mi][j] = __expf(acc[mi][ni][j] - mx); s += e[mi][j]; }
      s += __shfl_xor(s, 16);
      s += __shfl_xor(s, 32);
      float sc = 0.125f / s;  // SCALE = 64^-0.5
      int t = n0 + wc * 64 + ni * 16 + lo;
      u16* op = qT + ((size_t)bh * 4096 + t) * 64 + hi * 4;
#pragma unroll
      for (int mi = 0; mi < 4; ++mi) {
        union { u16 u[4]; uint2 v; } pk;
#pragma unroll
        for (int j = 0; j < 4; ++j) pk.u[j] = f2bf(e[mi][j] * sc);
        *(uint2*)(op + mi * 16) = pk.v;
      }
    }
  } else {
    u16* Cb = C + ((size_t)b * 1536 + m0) * 4096 + n0;
#pragma unroll
    for (int mi = 0; mi < 4; ++mi)
#pragma unroll
      for (int ni = 0; ni < 4; ++ni)
#pragma unroll
        for (int j = 0; j < 4; ++j) {
          int mm = wr * 64 + mi * 16 + hi * 4 + j;
          int nn = wc * 64 + ni * 16 + lo;
          Cb[(size_t)mm * 4096 + nn] = f2bf(acc[mi][ni][j]);
        }
  }
}

// ---------------- K7: final GEMM (pipelined 8-wave) + bias -> ybf, fused GN partials ------
// A = Wf [b][512][512]; B = qT head-chunked: k-chunk kt = head, d = lc*8
__launch_bounds__(512, 1)
__global__ void k_gemm_final(const u16* __restrict__ Wf, const u16* __restrict__ qT,
                             u16* __restrict__ Ybf, const float* __restrict__ bias,
                             float2* __restrict__ part2) {
  extern __shared__ char lds[];
  int b = blockIdx.z;
  int m0 = blockIdx.y * 128, n0 = blockIdx.x * 256;
  const u16* Ab = Wf + ((size_t)b * 512 + m0) * 512;
  const u16* Bq = qT + ((size_t)b * 8 * 4096 + n0) * 64;
  GEMM8W_CORE(Ab, BSRC_Q)
  u16* Yb = Ybf + ((size_t)b * 512 + m0) * 4096 + n0;
  float sm = 0.f, ssm = 0.f;
#pragma unroll
  for (int mi = 0; mi < 4; ++mi)
#pragma unroll
    for (int j = 0; j < 4; ++j) {
      int mm = wr * 64 + mi * 16 + hi * 4 + j;
      float bo = bias[m0 + mm];
#pragma unroll
      for (int ni = 0; ni < 4; ++ni) {
        int nn = wc * 64 + ni * 16 + lo;
        float vv = acc[mi][ni][j] + bo;
        sm += vv;
        ssm += vv * vv;
        Yb[(size_t)mm * 4096 + nn] = f2bf(vv);
      }
    }
#pragma unroll
  for (int off = 32; off; off >>= 1) { sm += __shfl_xor(sm, off); ssm += __shfl_xor(ssm, off); }
  float* sr = (float*)lds;
  float* ssr = sr + 8;
  __syncthreads();
  if (lane == 0) { sr[w] = sm; ssr[w] = ssm; }
  __syncthreads();
  if (tid == 0) {
    float2 o;
    o.x = 0.f; o.y = 0.f;
#pragma unroll
    for (int i = 0; i < 8; ++i) { o.x += sr[i]; o.y += ssr[i]; }
    part2[((size_t)b * 4 + blockIdx.y) * 16 + blockIdx.x] = o;
  }
}

// ---------------- K4: context partials with on-the-fly exp(k) ----------------
__global__ void k_context_part(const u16* __restrict__ qkv, float* __restrict__ ctxp,
                               float* __restrict__ spart) {
  int s = blockIdx.x, bh = blockIdx.y;
  int b = bh >> 3, h = bh & 7;
  int w = threadIdx.x >> 6, lane = threadIdx.x & 63;
  int hi = lane >> 4, lo = lane & 15;
  const u16* vb = qkv + ((size_t)b * 1536 + 1024 + h * 64) * 4096 + s * 256;
  const u16* kb = qkv + ((size_t)b * 1536 + 512 + h * 64) * 4096 + s * 256;
  int d = w * 16 + lo;
  f32x4 acc[4] = {};
  float ssum = 0.f;
#pragma unroll
  for (int st = 0; st < 8; ++st) {
    int nn = st * 32 + hi * 8;
    s16x8 braw = *(const s16x8*)(kb + (size_t)d * 4096 + nn);
    s16x8 bexp;
#pragma unroll
    for (int j = 0; j < 8; ++j) {
      float f = __expf(bf2f((u16)braw[j]));
      ssum += f;
      bexp[j] = (short)f2bf(f);
    }
#pragma unroll
    for (int ei = 0; ei < 4; ++ei) {
      s16x8 a = *(const s16x8*)(vb + (size_t)(ei * 16 + lo) * 4096 + nn);
      acc[ei] = MFMA_BF16(a, bexp, acc[ei]);
    }
  }
  float* cp = ctxp + ((size_t)bh * 16 + s) * 4096;
#pragma unroll
  for (int ei = 0; ei < 4; ++ei) {
    float4 o;
    o.x = acc[ei][0]; o.y = acc[ei][1]; o.z = acc[ei][2]; o.w = acc[ei][3];
    *(float4*)&cp[(size_t)d * 64 + ei * 16 + hi * 4] = o;
  }
  ssum += __shfl_xor(ssum, 16);
  ssum += __shfl_xor(ssum, 32);
  if (lane < 16) spart[((size_t)bh * 16 + s) * 64 + w * 16 + lane] = ssum;
}

// ---------------- K5: reduce ctx partials + normalize -> Bg [bh][d][e] bf16 ----------------
__global__ void k_ctx_reduce(const float* __restrict__ ctxp, const float* __restrict__ spart,
                             u16* __restrict__ Bg) {
  int q = blockIdx.x, bh = blockIdx.y;
  __shared__ float sinv[4];
  int tid = threadIdx.x;
  if (tid < 4) {
    int d = q * 4 + tid;
    float s = 0.f;
#pragma unroll
    for (int si = 0; si < 16; ++si) s += spart[((size_t)bh * 16 + si) * 64 + d];
    sinv[tid] = 1.f / s;
  }
  __syncthreads();
  int pos = q * 256 + tid;
  float v = 0.f;
#pragma unroll
  for (int si = 0; si < 16; ++si) v += ctxp[((size_t)bh * 16 + si) * 4096 + pos];
  Bg[(size_t)bh * 4096 + pos] = f2bf(v * sinv[(pos >> 6) & 3]);
}

// ---------------- K6: Wfused[b][m][h*64+d] = sum_e wout[m][h*64+e] * Bg[bh][d][e] ----------
__global__ void k_wfused(const u16* __restrict__ wout, const u16* __restrict__ Bg,
                         u16* __restrict__ Wf) {
  int bh = blockIdx.x;
  int b = bh >> 3, h = bh & 7;
  int w = threadIdx.x >> 6, lane = threadIdx.x & 63;
  int hi = lane >> 4, lo = lane & 15;
  const u16* Bb = Bg + (size_t)bh * 4096;
  const u16* Ab = wout + (size_t)h * 64;
  f32x4 acc[8][4] = {};
#pragma unroll
  for (int ks = 0; ks < 2; ++ks) {
    s16x8 bfr[4];
#pragma unroll
    for (int ni = 0; ni < 4; ++ni)
      bfr[ni] = *(const s16x8*)(Bb + (size_t)(ni * 16 + lo) * 64 + ks * 32 + hi * 8);
#pragma unroll
    for (int mi = 0; mi < 8; ++mi) {
      s16x8 a = *(const s16x8*)(Ab + (size_t)(w * 128 + mi * 16 + lo) * 512 + ks * 32 + hi * 8);
#pragma unroll
      for (int ni = 0; ni < 4; ++ni) acc[mi][ni] = MFMA_BF16(a, bfr[ni], acc[mi][ni]);
    }
  }
#pragma unroll
  for (int mi = 0; mi < 8; ++mi)
#pragma unroll
    for (int ni = 0; ni < 4; ++ni) {
      int m = w * 128 + mi * 16 + hi * 4;
      int d = ni * 16 + lo;
#pragma unroll
      for (int j = 0; j < 4; ++j)
        Wf[((size_t)b * 512 + m + j) * 512 + h * 64 + d] = f2bf(acc[mi][ni][j]);
    }
}

// ---------------- K8: GroupNorm normalize  ybf bf16 -> d_out f32 ----------------
__global__ void k_gn_norm(const u16* __restrict__ ybf, float* __restrict__ y,
                          const float2* __restrict__ part2,
                          const float* __restrict__ gamma, const float* __restrict__ beta) {
  int b = blockIdx.y;
  float s = 0.f, ss = 0.f;
#pragma unroll 8
  for (int i = 0; i < 64; ++i) { float2 pp = part2[b * 64 + i]; s += pp.x; ss += pp.y; }
  const float N = 512.f * 4096.f;
  float mu = s / N;
  float var = ss / N - mu * mu;
  float rstd = rsqrtf(var + 1e-5f);
  size_t base = ((size_t)b << 21) + (size_t)blockIdx.x * 16384;
  const s16x8* ip = (const s16x8*)(ybf + base);
  float4* opf = (float4*)(y + base);
#pragma unroll
  for (int i = 0; i < 8; ++i) {
    int idx = threadIdx.x + i * 256;
    int loc = (int)(blockIdx.x * 16384) + idx * 8;
    int c = loc >> 12;
    float g = gamma[c] * rstd, bt = beta[c];
    s16x8 v = ip[idx];
    float4 o0, o1;
    o0.x = (bf2f((u16)v[0]) - mu) * g + bt;
    o0.y = (bf2f((u16)v[1]) - mu) * g + bt;
    o0.z = (bf2f((u16)v[2]) - mu) * g + bt;
    o0.w = (bf2f((u16)v[3]) - mu) * g + bt;
    o1.x = (bf2f((u16)v[4]) - mu) * g + bt;
    o1.y = (bf2f((u16)v[5]) - mu) * g + bt;
    o1.z = (bf2f((u16)v[6]) - mu) * g + bt;
    o1.w = (bf2f((u16)v[7]) - mu) * g + bt;
    opf[idx * 2] = o0;
    opf[idx * 2 + 1] = o1;
  }
}

extern "C" void kernel_launch(void* const* d_in, const int* in_sizes, int n_in,
                              void* d_out, int out_size, void* d_ws, size_t ws_size,
                              hipStream_t stream) {
  const float* x     = (const float*)d_in[0];
  // d_in[1] = mask: adds 1e-12 to fp32 logits -> numerically dead; ignored.
  const float* wqkv  = (const float*)d_in[2];
  const float* wout  = (const float*)d_in[3];
  const float* bout  = (const float*)d_in[4];
  const float* gamma = (const float*)d_in[5];
  const float* beta  = (const float*)d_in[6];
  float* y = (float*)d_out;

  char* ws = (char*)d_ws;
  u16*    qkv_b = (u16*)ws;                   // 100,663,296 B [8][1536][4096] bf16 (k,v raw)
  u16*    ybf   = (u16*)ws;                   //  overlay: 33,554,432 B [8][512][4096] bf16
  u16*    xT    = (u16*)(ws + 100663296);     //  33,554,432 B [8][4096][512] bf16 (dead after K3)
  float*  ctxp  = (float*)(ws + 100663296);   //  overlay: 16,777,216 B [64][16][4096] f32
  float*  spart = (float*)(ws + 117440512);   //     262,144 B [64][16][64] f32
  u16*    Bg    = (u16*)(ws + 117702656);     //     524,288 B [64][4096] bf16
  u16*    qT    = (u16*)(ws + 134217728);     //  33,554,432 B [64][4096][64] bf16
  u16*    wqkvb = (u16*)(ws + 167772160);     //   1,572,864 B
  u16*    woutb = (u16*)(ws + 169345024);     //     524,288 B
  u16*    Wfused= (u16*)(ws + 169869312);     //   4,194,304 B [8][512][512] bf16
  float2* part2 = (float2*)(ws + 174063616);  //       8,192 B

  const int GEMM_LDS = 147456;
  (void)hipFuncSetAttribute((const void*)k_gemm_qkv,
                            hipFuncAttributeMaxDynamicSharedMemorySize, GEMM_LDS);
  (void)hipFuncSetAttribute((const void*)k_gemm_final,
                            hipFuncAttributeMaxDynamicSharedMemorySize, GEMM_LDS);

  k_convert_w<<<1024, 256, 0, stream>>>(wqkv, wout, wqkvb, woutb);
  {
    dim3 g(64, 8, 8);
    k_transpose_x<<<g, 256, 0, stream>>>(x, xT);
  }
  {
    dim3 g(16, 12, 8);
    k_gemm_qkv<<<g, 512, GEMM_LDS, stream>>>(wqkvb, xT, qkv_b, qT);
  }
  {
    dim3 g(16, 64);
    k_context_part<<<g, 256, 0, stream>>>(qkv_b, ctxp, spart);
  }
  {
    dim3 g(16, 64);
    k_ctx_reduce<<<g, 256, 0, stream>>>(ctxp, spart, Bg);
  }
  k_wfused<<<64, 256, 0, stream>>>(woutb, Bg, Wfused);
  {
    dim3 g(16, 4, 8);
    k_gemm_final<<<g, 512, GEMM_LDS, stream>>>(Wfused, qT, ybf, bout, part2);
  }
  {
    dim3 g(128, 8);
    k_gn_norm<<<g, 256, 0, stream>>>(ybf, y, part2, gamma, beta);
  }
}